// Round 1
// baseline (1289.451 us; speedup 1.0000x reference)
//
#include <hip/hip_runtime.h>
#include <math.h>

// Problem constants
#define BB 8
#define NN 4096      // 64*64 tokens
#define CD 512       // channels
#define HH 8
#define DD 64
#define OC3 1536     // 3*hidden
#define NSPLIT 16

// ---------------------------------------------------------------------------
// Tiled fp32 GEMM: C[M,N] = A[M,K] @ B[K,N] (+ bias[row]), batched via grid.z
// block 16x16, 64x64 tile, 4x4 microtile, KT=16
// ---------------------------------------------------------------------------
__global__ __launch_bounds__(256) void gemm_kernel(
    const float* __restrict__ A, long sA,
    const float* __restrict__ Bm, long sB,
    float* __restrict__ Cm, long sC,
    const float* __restrict__ bias,
    int M, int N, int K)
{
    int bz = blockIdx.z;
    A  += (long)bz * sA;
    Bm += (long)bz * sB;
    Cm += (long)bz * sC;
    int m0 = blockIdx.y * 64, n0 = blockIdx.x * 64;

    __shared__ float As[16][64];
    __shared__ float Bs[16][64];

    int tx = threadIdx.x, ty = threadIdx.y;
    int t = ty * 16 + tx;

    float acc[4][4] = {};

    for (int k0 = 0; k0 < K; k0 += 16) {
        #pragma unroll
        for (int i = 0; i < 4; ++i) {
            int idx = t + i * 256;
            int kk = idx & 15, mm = idx >> 4;
            As[kk][mm] = A[(long)(m0 + mm) * K + k0 + kk];
        }
        #pragma unroll
        for (int i = 0; i < 4; ++i) {
            int idx = t + i * 256;
            int nn = idx & 63, kk = idx >> 6;
            Bs[kk][nn] = Bm[(long)(k0 + kk) * N + n0 + nn];
        }
        __syncthreads();
        #pragma unroll
        for (int kk = 0; kk < 16; ++kk) {
            float4 a4 = *reinterpret_cast<const float4*>(&As[kk][ty * 4]);
            float4 b4 = *reinterpret_cast<const float4*>(&Bs[kk][tx * 4]);
            float av[4] = {a4.x, a4.y, a4.z, a4.w};
            float bv[4] = {b4.x, b4.y, b4.z, b4.w};
            #pragma unroll
            for (int i = 0; i < 4; ++i)
                #pragma unroll
                for (int j = 0; j < 4; ++j)
                    acc[i][j] += av[i] * bv[j];
        }
        __syncthreads();
    }

    #pragma unroll
    for (int i = 0; i < 4; ++i) {
        int mm = m0 + ty * 4 + i;
        float bb = bias ? bias[mm] : 0.f;
        #pragma unroll
        for (int j = 0; j < 4; ++j)
            Cm[(long)mm * N + n0 + tx * 4 + j] = acc[i][j] + bb;
    }
}

// ---------------------------------------------------------------------------
// q softmax over head_dim (axis d, 64 elems, stride NN), then * scale
// one thread per (b,h,n) column
// ---------------------------------------------------------------------------
__global__ __launch_bounds__(256) void softmax_q_kernel(float* __restrict__ qkv)
{
    long idx = (long)blockIdx.x * 256 + threadIdx.x;   // B*H*N total
    int n = (int)(idx & (NN - 1));
    long bh = idx >> 12;
    int h = (int)(bh & (HH - 1));
    int b = (int)(bh >> 3);
    float* base = qkv + ((long)b * OC3 + (long)h * DD) * NN + n;

    float v[DD];
    float mx = -INFINITY;
    #pragma unroll
    for (int d = 0; d < DD; ++d) {
        v[d] = base[(long)d * NN];
        mx = fmaxf(mx, v[d]);
    }
    float s = 0.f;
    #pragma unroll
    for (int d = 0; d < DD; ++d) {
        v[d] = expf(v[d] - mx);
        s += v[d];
    }
    float r = 0.125f / s;   // scale = 64^-0.5 = 0.125
    #pragma unroll
    for (int d = 0; d < DD; ++d)
        base[(long)d * NN] = v[d] * r;
}

// ---------------------------------------------------------------------------
// k softmax over tokens (axis n, 4096 contiguous). one block per row.
// ---------------------------------------------------------------------------
__global__ __launch_bounds__(256) void softmax_k_kernel(float* __restrict__ qkv)
{
    int row = blockIdx.x;              // b*512 + hd
    int b = row >> 9;
    int hd = row & (CD - 1);
    float* base = qkv + ((long)b * OC3 + CD + hd) * NN;
    int t = threadIdx.x;

    float v[16];
    #pragma unroll
    for (int i = 0; i < 16; ++i) v[i] = base[t + i * 256];

    __shared__ float red[256];
    float mx = -INFINITY;
    #pragma unroll
    for (int i = 0; i < 16; ++i) mx = fmaxf(mx, v[i]);
    red[t] = mx; __syncthreads();
    for (int off = 128; off > 0; off >>= 1) {
        if (t < off) red[t] = fmaxf(red[t], red[t + off]);
        __syncthreads();
    }
    mx = red[0]; __syncthreads();

    float s = 0.f;
    #pragma unroll
    for (int i = 0; i < 16; ++i) {
        v[i] = expf(v[i] - mx);
        s += v[i];
    }
    red[t] = s; __syncthreads();
    for (int off = 128; off > 0; off >>= 1) {
        if (t < off) red[t] += red[t + off];
        __syncthreads();
    }
    float inv = 1.f / red[0];

    #pragma unroll
    for (int i = 0; i < 16; ++i) base[t + i * 256] = v[i] * inv;
}

// ---------------------------------------------------------------------------
// context partials: ctxp[bh][sp][d][e] = sum over n-slice of k_s[d,n]*v[e,n]
// block (16,16), grid (B*H, NSPLIT). each thread 4x4 outputs.
// ---------------------------------------------------------------------------
__global__ __launch_bounds__(256) void context_part_kernel(
    const float* __restrict__ qkv, float* __restrict__ ctxp)
{
    int bh = blockIdx.x;               // 0..63
    int sp = blockIdx.y;               // 0..15
    int b = bh >> 3, h = bh & 7;
    const float* kb = qkv + ((long)b * OC3 + CD + (long)h * DD) * NN;
    const float* vb = qkv + ((long)b * OC3 + 2 * CD + (long)h * DD) * NN;

    __shared__ float ks[64][65];
    __shared__ float vs[64][65];
    int tx = threadIdx.x, ty = threadIdx.y;
    int t = ty * 16 + tx;

    float acc[4][4] = {};

    int nbeg = sp * (NN / NSPLIT);
    for (int n0 = nbeg; n0 < nbeg + NN / NSPLIT; n0 += 64) {
        #pragma unroll
        for (int i = 0; i < 16; ++i) {
            int idx = t + i * 256;
            int r = idx >> 6, cc = idx & 63;
            ks[r][cc] = kb[(long)r * NN + n0 + cc];
            vs[r][cc] = vb[(long)r * NN + n0 + cc];
        }
        __syncthreads();
        #pragma unroll
        for (int nn = 0; nn < 64; ++nn) {
            float kd[4], vd[4];
            #pragma unroll
            for (int i = 0; i < 4; ++i) {
                kd[i] = ks[ty * 4 + i][nn];
                vd[i] = vs[tx * 4 + i][nn];
            }
            #pragma unroll
            for (int i = 0; i < 4; ++i)
                #pragma unroll
                for (int j = 0; j < 4; ++j)
                    acc[i][j] += kd[i] * vd[j];
        }
        __syncthreads();
    }

    #pragma unroll
    for (int i = 0; i < 4; ++i)
        #pragma unroll
        for (int j = 0; j < 4; ++j)
            ctxp[(((long)bh * NSPLIT + sp) * DD + ty * 4 + i) * DD + tx * 4 + j] = acc[i][j];
}

// ---------------------------------------------------------------------------
// reduce partials in fp64, apply 1/N (the v/n scaling)
// ---------------------------------------------------------------------------
__global__ __launch_bounds__(256) void context_reduce_kernel(
    const float* __restrict__ ctxp, float* __restrict__ ctx)
{
    int idx = blockIdx.x * 256 + threadIdx.x;      // B*H*64*64 = 262144
    int bh = idx >> 12;
    int de = idx & 4095;
    double s = 0.0;
    #pragma unroll
    for (int sp = 0; sp < NSPLIT; ++sp)
        s += (double)ctxp[((long)bh * NSPLIT + sp) * 4096 + de];
    ctx[idx] = (float)(s * (1.0 / (double)NN));
}

// ---------------------------------------------------------------------------
// fold w_out into per-batch M: M[b][c][h*64+d] = sum_e w_out[c][h*64+e]*ctx[b,h,d,e]
// ---------------------------------------------------------------------------
__global__ __launch_bounds__(256) void fold_wout_kernel(
    const float* __restrict__ w_out, const float* __restrict__ ctx,
    float* __restrict__ Mm)
{
    long idx = (long)blockIdx.x * 256 + threadIdx.x;   // B*512*512
    int hd = (int)(idx & (CD - 1));
    int c = (int)((idx >> 9) & (CD - 1));
    int b = (int)(idx >> 18);
    int h = hd >> 6, d = hd & 63;
    const float* wrow = w_out + (long)c * CD + (long)h * DD;
    const float* crow = ctx + (((long)(b * HH + h) * DD + d) * DD);
    float s = 0.f;
    #pragma unroll
    for (int e = 0; e < DD; ++e) s += wrow[e] * crow[e];
    Mm[idx] = s;
}

// ---------------------------------------------------------------------------
// channel LayerNorm over c=512 (stride NN), fp64 stats; writes final output
// y lives in the (dead) k_s region of qkv: offset 512*NN within each batch
// ---------------------------------------------------------------------------
__global__ __launch_bounds__(256) void layernorm_kernel(
    const float* __restrict__ qkv, const float* __restrict__ g,
    float* __restrict__ out)
{
    long idx = (long)blockIdx.x * 256 + threadIdx.x;   // B*N = 32768
    int n = (int)(idx & (NN - 1));
    int b = (int)(idx >> 12);
    const float* col = qkv + (long)b * OC3 * NN + (long)CD * NN + n;

    double s = 0.0, ss = 0.0;
    for (int c = 0; c < CD; ++c) {
        float v = col[(long)c * NN];
        s += (double)v;
        ss += (double)v * (double)v;
    }
    double mean = s * (1.0 / CD);
    double var = ss * (1.0 / CD) - mean * mean;
    double inv = 1.0 / sqrt(var + 1e-5);
    float meanf = (float)mean, invf = (float)inv;

    float* ocol = out + (long)b * CD * NN + n;
    for (int c = 0; c < CD; ++c)
        ocol[(long)c * NN] = (col[(long)c * NN] - meanf) * invf * g[c];
}

// ---------------------------------------------------------------------------
extern "C" void kernel_launch(void* const* d_in, const int* in_sizes, int n_in,
                              void* d_out, int out_size, void* d_ws, size_t ws_size,
                              hipStream_t stream)
{
    const float* x     = (const float*)d_in[0];
    const float* w_qkv = (const float*)d_in[1];
    const float* w_out = (const float*)d_in[2];
    const float* b_out = (const float*)d_in[3];
    const float* g     = (const float*)d_in[4];
    float* out = (float*)d_out;

    float* ws   = (float*)d_ws;
    float* qkv  = ws;                                   // B*1536*4096 = 50,331,648 f
    float* ctxp = qkv + (long)BB * OC3 * NN;            // 64*16*4096  =  4,194,304 f
    float* ctx  = ctxp + (long)BB * HH * NSPLIT * DD * DD; //           262,144 f
    float* Mm   = ctx + (long)BB * HH * DD * DD;        // 8*512*512   =  2,097,152 f

    dim3 blk(16, 16);

    // 1) qkv = w_qkv @ x   (per batch: 1536x512 @ 512x4096)
    gemm_kernel<<<dim3(NN / 64, OC3 / 64, BB), blk, 0, stream>>>(
        w_qkv, 0L, x, (long)CD * NN, qkv, (long)OC3 * NN, nullptr,
        OC3, NN, CD);

    // 2) softmaxes (in place), v/n folded into context reduce
    softmax_q_kernel<<<(BB * HH * NN) / 256, 256, 0, stream>>>(qkv);
    softmax_k_kernel<<<BB * CD, 256, 0, stream>>>(qkv);

    // 3) context = k_s @ v^T / N  (partials + fp64 reduce)
    context_part_kernel<<<dim3(BB * HH, NSPLIT), blk, 0, stream>>>(qkv, ctxp);
    context_reduce_kernel<<<(BB * HH * DD * DD) / 256, 256, 0, stream>>>(ctxp, ctx);

    // 4) M_b = fold(w_out, ctx)
    fold_wout_kernel<<<(BB * CD * CD) / 256, 256, 0, stream>>>(w_out, ctx, Mm);

    // 5) y = M_b @ q_s + b_out   -> stored into the dead k_s region of qkv
    gemm_kernel<<<dim3(NN / 64, CD / 64, BB), blk, 0, stream>>>(
        Mm, (long)CD * CD, qkv, (long)OC3 * NN,
        qkv + (long)CD * NN, (long)OC3 * NN, b_out,
        CD, NN, CD);

    // 6) channel LayerNorm -> d_out
    layernorm_kernel<<<(BB * NN) / 256, 256, 0, stream>>>(qkv, g, out);
}

// Round 2
// 965.920 us; speedup vs baseline: 1.3349x; 1.3349x over previous
//
#include <hip/hip_runtime.h>
#include <math.h>

// Problem constants
#define BB 8
#define NN 4096      // 64*64 tokens
#define CD 512       // channels
#define HH 8
#define DD 64
#define OC3 1536     // 3*hidden
#define NSPLIT 16

// ---------------------------------------------------------------------------
// Transpose: out[c][r] = in[r][c].  block (32,8), 32x32 LDS tile.
// ---------------------------------------------------------------------------
__global__ __launch_bounds__(256) void transpose_kernel(
    const float* __restrict__ in, float* __restrict__ outp, int R, int C)
{
    __shared__ float tile[32][33];
    int bx = blockIdx.x * 32, by = blockIdx.y * 32;
    int tx = threadIdx.x, ty = threadIdx.y;
    #pragma unroll
    for (int i = 0; i < 4; ++i)
        tile[ty + i * 8][tx] = in[(long)(by + ty + i * 8) * C + bx + tx];
    __syncthreads();
    #pragma unroll
    for (int i = 0; i < 4; ++i)
        outp[(long)(bx + ty + i * 8) * R + by + tx] = tile[tx][ty + i * 8];
}

// ---------------------------------------------------------------------------
// fp32 GEMM with pre-transposed A:  C[M,N] = At^T @ B (+bias)
// At layout [K][M] (ld ldA), B [K][N], C [M][N]. Batched via grid.z.
// block 16x16, tile 128x128, KT=16, 8x8 microtile (split 4+4 at +64).
// ---------------------------------------------------------------------------
__global__ __launch_bounds__(256) void gemm_t_kernel(
    const float* __restrict__ At, long sA, int ldA,
    const float* __restrict__ Bm, long sB, int ldB,
    float* __restrict__ Cm, long sC, int ldC,
    const float* __restrict__ bias,
    int K)
{
    int bz = blockIdx.z;
    At += (long)bz * sA;
    Bm += (long)bz * sB;
    Cm += (long)bz * sC;
    int m0 = blockIdx.y * 128, n0 = blockIdx.x * 128;

    __shared__ float As[16][128];
    __shared__ float Bs[16][128];

    int tx = threadIdx.x, ty = threadIdx.y;
    int t = ty * 16 + tx;
    int lk = t >> 5;      // 0..7
    int lc = t & 31;      // float4 column index 0..31

    float acc[8][8] = {};

    for (int k0 = 0; k0 < K; k0 += 16) {
        #pragma unroll
        for (int i = 0; i < 2; ++i) {
            int kk = lk + i * 8;
            float4 va = *reinterpret_cast<const float4*>(&At[(long)(k0 + kk) * ldA + m0 + 4 * lc]);
            *reinterpret_cast<float4*>(&As[kk][4 * lc]) = va;
            float4 vb = *reinterpret_cast<const float4*>(&Bm[(long)(k0 + kk) * ldB + n0 + 4 * lc]);
            *reinterpret_cast<float4*>(&Bs[kk][4 * lc]) = vb;
        }
        __syncthreads();
        #pragma unroll
        for (int kk = 0; kk < 16; ++kk) {
            float a[8], b[8];
            *reinterpret_cast<float4*>(&a[0]) = *reinterpret_cast<const float4*>(&As[kk][ty * 4]);
            *reinterpret_cast<float4*>(&a[4]) = *reinterpret_cast<const float4*>(&As[kk][64 + ty * 4]);
            *reinterpret_cast<float4*>(&b[0]) = *reinterpret_cast<const float4*>(&Bs[kk][tx * 4]);
            *reinterpret_cast<float4*>(&b[4]) = *reinterpret_cast<const float4*>(&Bs[kk][64 + tx * 4]);
            #pragma unroll
            for (int i = 0; i < 8; ++i)
                #pragma unroll
                for (int j = 0; j < 8; ++j)
                    acc[i][j] += a[i] * b[j];
        }
        __syncthreads();
    }

    #pragma unroll
    for (int ih = 0; ih < 2; ++ih)
        #pragma unroll
        for (int i = 0; i < 4; ++i) {
            int row = m0 + ih * 64 + ty * 4 + i;
            float bb = bias ? bias[row] : 0.f;
            #pragma unroll
            for (int jh = 0; jh < 2; ++jh) {
                float4 o;
                o.x = acc[ih * 4 + i][jh * 4 + 0] + bb;
                o.y = acc[ih * 4 + i][jh * 4 + 1] + bb;
                o.z = acc[ih * 4 + i][jh * 4 + 2] + bb;
                o.w = acc[ih * 4 + i][jh * 4 + 3] + bb;
                *reinterpret_cast<float4*>(&Cm[(long)row * ldC + n0 + jh * 64 + tx * 4]) = o;
            }
        }
}

// ---------------------------------------------------------------------------
// q softmax over head_dim (axis d, 64 elems, stride NN), then * scale
// ---------------------------------------------------------------------------
__global__ __launch_bounds__(256) void softmax_q_kernel(float* __restrict__ qkv)
{
    long idx = (long)blockIdx.x * 256 + threadIdx.x;   // B*H*N total
    int n = (int)(idx & (NN - 1));
    long bh = idx >> 12;
    int h = (int)(bh & (HH - 1));
    int b = (int)(bh >> 3);
    float* base = qkv + ((long)b * OC3 + (long)h * DD) * NN + n;

    float v[DD];
    float mx = -INFINITY;
    #pragma unroll
    for (int d = 0; d < DD; ++d) {
        v[d] = base[(long)d * NN];
        mx = fmaxf(mx, v[d]);
    }
    float s = 0.f;
    #pragma unroll
    for (int d = 0; d < DD; ++d) {
        v[d] = expf(v[d] - mx);
        s += v[d];
    }
    float r = 0.125f / s;   // scale = 64^-0.5 = 0.125
    #pragma unroll
    for (int d = 0; d < DD; ++d)
        base[(long)d * NN] = v[d] * r;
}

// ---------------------------------------------------------------------------
// k softmax over tokens (axis n, 4096 contiguous). one block per row.
// ---------------------------------------------------------------------------
__global__ __launch_bounds__(256) void softmax_k_kernel(float* __restrict__ qkv)
{
    int row = blockIdx.x;              // b*512 + hd
    int b = row >> 9;
    int hd = row & (CD - 1);
    float* base = qkv + ((long)b * OC3 + CD + hd) * NN;
    int t = threadIdx.x;

    float v[16];
    #pragma unroll
    for (int i = 0; i < 16; ++i) v[i] = base[t + i * 256];

    __shared__ float red[256];
    float mx = -INFINITY;
    #pragma unroll
    for (int i = 0; i < 16; ++i) mx = fmaxf(mx, v[i]);
    red[t] = mx; __syncthreads();
    for (int off = 128; off > 0; off >>= 1) {
        if (t < off) red[t] = fmaxf(red[t], red[t + off]);
        __syncthreads();
    }
    mx = red[0]; __syncthreads();

    float s = 0.f;
    #pragma unroll
    for (int i = 0; i < 16; ++i) {
        v[i] = expf(v[i] - mx);
        s += v[i];
    }
    red[t] = s; __syncthreads();
    for (int off = 128; off > 0; off >>= 1) {
        if (t < off) red[t] += red[t + off];
        __syncthreads();
    }
    float inv = 1.f / red[0];

    #pragma unroll
    for (int i = 0; i < 16; ++i) base[t + i * 256] = v[i] * inv;
}

// ---------------------------------------------------------------------------
// context partials: ctxp[bh][sp][d][e] = sum over n-slice of k_s[d,n]*v[e,n]
// ---------------------------------------------------------------------------
__global__ __launch_bounds__(256) void context_part_kernel(
    const float* __restrict__ qkv, float* __restrict__ ctxp)
{
    int bh = blockIdx.x;               // 0..63
    int sp = blockIdx.y;               // 0..15
    int b = bh >> 3, h = bh & 7;
    const float* kb = qkv + ((long)b * OC3 + CD + (long)h * DD) * NN;
    const float* vb = qkv + ((long)b * OC3 + 2 * CD + (long)h * DD) * NN;

    __shared__ float ks[64][65];
    __shared__ float vs[64][65];
    int tx = threadIdx.x, ty = threadIdx.y;
    int t = ty * 16 + tx;

    float acc[4][4] = {};

    int nbeg = sp * (NN / NSPLIT);
    for (int n0 = nbeg; n0 < nbeg + NN / NSPLIT; n0 += 64) {
        #pragma unroll
        for (int i = 0; i < 16; ++i) {
            int idx = t + i * 256;
            int r = idx >> 6, cc = idx & 63;
            ks[r][cc] = kb[(long)r * NN + n0 + cc];
            vs[r][cc] = vb[(long)r * NN + n0 + cc];
        }
        __syncthreads();
        #pragma unroll
        for (int nn = 0; nn < 64; ++nn) {
            float kd[4], vd[4];
            #pragma unroll
            for (int i = 0; i < 4; ++i) {
                kd[i] = ks[ty * 4 + i][nn];
                vd[i] = vs[tx * 4 + i][nn];
            }
            #pragma unroll
            for (int i = 0; i < 4; ++i)
                #pragma unroll
                for (int j = 0; j < 4; ++j)
                    acc[i][j] += kd[i] * vd[j];
        }
        __syncthreads();
    }

    #pragma unroll
    for (int i = 0; i < 4; ++i)
        #pragma unroll
        for (int j = 0; j < 4; ++j)
            ctxp[(((long)bh * NSPLIT + sp) * DD + ty * 4 + i) * DD + tx * 4 + j] = acc[i][j];
}

// ---------------------------------------------------------------------------
// reduce partials in fp64, apply 1/N (the v/n scaling)
// ---------------------------------------------------------------------------
__global__ __launch_bounds__(256) void context_reduce_kernel(
    const float* __restrict__ ctxp, float* __restrict__ ctx)
{
    int idx = blockIdx.x * 256 + threadIdx.x;      // B*H*64*64 = 262144
    int bh = idx >> 12;
    int de = idx & 4095;
    double s = 0.0;
    #pragma unroll
    for (int sp = 0; sp < NSPLIT; ++sp)
        s += (double)ctxp[((long)bh * NSPLIT + sp) * 4096 + de];
    ctx[idx] = (float)(s * (1.0 / (double)NN));
}

// ---------------------------------------------------------------------------
// fold w_out into per-batch Mt (TRANSPOSED: Mt[b][hd][c]):
//   Mt[b][hd][c] = sum_e w_out[c][h*64+e] * ctx[b,h,d,e],  hd = h*64+d
// idx fast dim = c  -> coalesced writes
// ---------------------------------------------------------------------------
__global__ __launch_bounds__(256) void fold_wout_kernel(
    const float* __restrict__ w_out, const float* __restrict__ ctx,
    float* __restrict__ Mt)
{
    long idx = (long)blockIdx.x * 256 + threadIdx.x;   // B*512*512
    int c  = (int)(idx & (CD - 1));
    int hd = (int)((idx >> 9) & (CD - 1));
    int b  = (int)(idx >> 18);
    int h = hd >> 6, d = hd & 63;
    const float* wrow = w_out + (long)c * CD + (long)h * DD;
    const float* crow = ctx + (((long)(b * HH + h) * DD + d) * DD);
    float s = 0.f;
    #pragma unroll
    for (int e = 0; e < DD; e += 4) {
        float4 wv = *reinterpret_cast<const float4*>(&wrow[e]);
        float4 cv = *reinterpret_cast<const float4*>(&crow[e]);
        s += wv.x * cv.x + wv.y * cv.y + wv.z * cv.z + wv.w * cv.w;
    }
    Mt[idx] = s;
}

// ---------------------------------------------------------------------------
// channel LayerNorm over c=512 (stride NN), fp64 stats; writes final output
// ---------------------------------------------------------------------------
__global__ __launch_bounds__(256) void layernorm_kernel(
    const float* __restrict__ qkv, const float* __restrict__ g,
    float* __restrict__ out)
{
    long idx = (long)blockIdx.x * 256 + threadIdx.x;   // B*N = 32768
    int n = (int)(idx & (NN - 1));
    int b = (int)(idx >> 12);
    const float* col = qkv + (long)b * OC3 * NN + (long)CD * NN + n;

    double s = 0.0, ss = 0.0;
    for (int c = 0; c < CD; ++c) {
        float v = col[(long)c * NN];
        s += (double)v;
        ss += (double)v * (double)v;
    }
    double mean = s * (1.0 / CD);
    double var = ss * (1.0 / CD) - mean * mean;
    double inv = 1.0 / sqrt(var + 1e-5);
    float meanf = (float)mean, invf = (float)inv;

    float* ocol = out + (long)b * CD * NN + n;
    for (int c = 0; c < CD; ++c)
        ocol[(long)c * NN] = (col[(long)c * NN] - meanf) * invf * g[c];
}

// ---------------------------------------------------------------------------
extern "C" void kernel_launch(void* const* d_in, const int* in_sizes, int n_in,
                              void* d_out, int out_size, void* d_ws, size_t ws_size,
                              hipStream_t stream)
{
    const float* x     = (const float*)d_in[0];
    const float* w_qkv = (const float*)d_in[1];
    const float* w_out = (const float*)d_in[2];
    const float* b_out = (const float*)d_in[3];
    const float* g     = (const float*)d_in[4];
    float* out = (float*)d_out;

    float* ws   = (float*)d_ws;
    float* qkv  = ws;                                      // 50,331,648 f
    float* ctxp = qkv + (long)BB * OC3 * NN;               //  4,194,304 f
    float* ctx  = ctxp + (long)BB * HH * NSPLIT * DD * DD; //    262,144 f
    float* Mt   = ctx + (long)BB * HH * DD * DD;           //  2,097,152 f
    float* wt   = Mt + (long)BB * CD * CD;                 //    786,432 f (w_qkv^T)

    // 0) transpose w_qkv (1536x512) -> wt (512x1536)
    transpose_kernel<<<dim3(CD / 32, OC3 / 32), dim3(32, 8), 0, stream>>>(
        w_qkv, wt, OC3, CD);

    // 1) qkv = w_qkv @ x   (per batch: 1536x512 @ 512x4096), A^T staged
    gemm_t_kernel<<<dim3(NN / 128, OC3 / 128, BB), dim3(16, 16), 0, stream>>>(
        wt, 0L, OC3,
        x, (long)CD * NN, NN,
        qkv, (long)OC3 * NN, NN,
        nullptr, CD);

    // 2) softmaxes (in place)
    softmax_q_kernel<<<(BB * HH * NN) / 256, 256, 0, stream>>>(qkv);
    softmax_k_kernel<<<BB * CD, 256, 0, stream>>>(qkv);

    // 3) context = k_s @ v^T / N  (partials + fp64 reduce)
    context_part_kernel<<<dim3(BB * HH, NSPLIT), dim3(16, 16), 0, stream>>>(qkv, ctxp);
    context_reduce_kernel<<<(BB * HH * DD * DD) / 256, 256, 0, stream>>>(ctxp, ctx);

    // 4) Mt = fold(w_out, ctx), already transposed for gemm
    fold_wout_kernel<<<(BB * CD * CD) / 256, 256, 0, stream>>>(w_out, ctx, Mt);

    // 5) y = M_b @ q_s + b_out   -> stored into the dead k_s region of qkv
    gemm_t_kernel<<<dim3(NN / 128, CD / 128, BB), dim3(16, 16), 0, stream>>>(
        Mt, (long)CD * CD, CD,
        qkv, (long)OC3 * NN, NN,
        qkv + (long)CD * NN, (long)OC3 * NN, NN,
        b_out, CD);

    // 6) channel LayerNorm -> d_out
    layernorm_kernel<<<(BB * NN) / 256, 256, 0, stream>>>(qkv, g, out);
}

// Round 3
// 616.378 us; speedup vs baseline: 2.0920x; 1.5671x over previous
//
#include <hip/hip_runtime.h>
#include <math.h>

// Problem constants
#define BB 8
#define NN 4096      // 64*64 tokens
#define CD 512       // channels
#define HH 8
#define DD 64
#define OC3 1536     // 3*hidden
#define NSPLIT 16

typedef _Float16 f16;
typedef _Float16 half8 __attribute__((ext_vector_type(8)));
typedef _Float16 half4v __attribute__((ext_vector_type(4)));
typedef float f32x4 __attribute__((ext_vector_type(4)));

__device__ __forceinline__ void gload_lds16(const void* g, void* l) {
    __builtin_amdgcn_global_load_lds(
        (const __attribute__((address_space(1))) unsigned int*)g,
        (__attribute__((address_space(3))) unsigned int*)l, 16, 0, 0);
}

// ---------------------------------------------------------------------------
// split w_qkv [1536][512] f32 -> wh, wl [1536][512] f16, scaled by 64
// ---------------------------------------------------------------------------
__global__ __launch_bounds__(256) void split_w_kernel(
    const float* __restrict__ w, f16* __restrict__ wh, f16* __restrict__ wl)
{
    int idx = blockIdx.x * 256 + threadIdx.x;      // OC3*CD/4 = 196608 total
    float4 v = ((const float4*)w)[idx];
    float a[4] = {v.x, v.y, v.z, v.w};
    half4v h, l;
    #pragma unroll
    for (int i = 0; i < 4; ++i) {
        float s = a[i] * 64.f;
        f16 hh = (f16)s;
        h[i] = hh;
        l[i] = (f16)(s - (float)hh);
    }
    *(half4v*)(&wh[(long)idx * 4]) = h;
    *(half4v*)(&wl[(long)idx * 4]) = l;
}

// ---------------------------------------------------------------------------
// split + transpose x [b][512 k][4096 n] f32 -> xth, xtl [b][4096 n][512 k]
// f16, scaled by 16.  block (32,8), 32x32 tile.
// ---------------------------------------------------------------------------
__global__ __launch_bounds__(256) void split_x_kernel(
    const float* __restrict__ x, f16* __restrict__ xth, f16* __restrict__ xtl)
{
    __shared__ float tile[32][33];
    int b = blockIdx.z;
    int n0 = blockIdx.x * 32, k0 = blockIdx.y * 32;
    const float* xb = x + (long)b * CD * NN;
    int tx = threadIdx.x, ty = threadIdx.y;
    #pragma unroll
    for (int i = 0; i < 4; ++i)
        tile[ty + i * 8][tx] = xb[(long)(k0 + ty + i * 8) * NN + n0 + tx];
    __syncthreads();
    long obase = (long)b * NN * CD;
    #pragma unroll
    for (int i = 0; i < 4; ++i) {
        int n = n0 + ty + i * 8;
        float s = tile[tx][ty + i * 8] * 16.f;
        f16 h = (f16)s;
        f16 l = (f16)(s - (float)h);
        xth[obase + (long)n * CD + k0 + tx] = h;
        xtl[obase + (long)n * CD + k0 + tx] = l;
    }
}

// ---------------------------------------------------------------------------
// qkv = w_qkv @ x via split-f16 MFMA (3 products: hh + hl + lh), fp32 accum.
// A = wh/wl [M][K], B = xth/xtl [N][K] (pre-transposed). C = qkv [M][N].
// Block 256 (4 waves 2x2), tile 128x128, wave tile 64x64, KT=32,
// mfma_f32_16x16x32_f16.  LDS: 4 arrays [128 rows][32 k] f16, XOR-swizzled
// 16B chunks (chunk' = chunk ^ ((row>>1)&3)) staged via global_load_lds with
// pre-swizzled global source (rule: linear dest + inv-swz source + swz read).
// Epilogue scales by 2^-10 (w was x64, x was x16).
// ---------------------------------------------------------------------------
__global__ __launch_bounds__(256) void qkv_mfma_kernel(
    const f16* __restrict__ wh, const f16* __restrict__ wl,
    const f16* __restrict__ xth, const f16* __restrict__ xtl,
    float* __restrict__ qkv)
{
    __shared__ f16 lds[4][128 * 32];     // Ah, Al, Bh, Bl ; 8 KB each
    int b = blockIdx.z;
    int n0 = blockIdx.x * 128, m0 = blockIdx.y * 128;
    int t = threadIdx.x;
    int lane = t & 63, wid = t >> 6;
    int wy = wid >> 1, wx = wid & 1;

    // staging lane constants: physical chunk = lane&3, row-in-group = lane>>2
    // logical chunk gathered = (lane&3) ^ ((row>>1)&3), row bits from lane>>2
    int cl = (lane & 3) ^ ((lane >> 3) & 3);
    long g_lane = (long)(lane >> 2) * 1024 + (long)cl * 16;   // bytes

    const char* gA_h = (const char*)wh + (long)m0 * 1024;
    const char* gA_l = (const char*)wl + (long)m0 * 1024;
    const char* gB_h = (const char*)xth + (long)b * ((long)NN * CD * 2) + (long)n0 * 1024;
    const char* gB_l = (const char*)xtl + (long)b * ((long)NN * CD * 2) + (long)n0 * 1024;

    char* ldsb = (char*)&lds[0][0];
    int rb0 = wid * 32;                  // this wave stages rows rb0..rb0+31

    // frag-read lane constants: want logical chunk (lane>>4); read physical
    int cp = (lane >> 4) ^ (((lane & 15) >> 1) & 3);
    long offA = (long)(wy * 64 + (lane & 15)) * 64 + (long)cp * 16;
    long offB = (long)(wx * 64 + (lane & 15)) * 64 + (long)cp * 16;

    f32x4 acc[4][4];
    #pragma unroll
    for (int i = 0; i < 4; ++i)
        #pragma unroll
        for (int j = 0; j < 4; ++j)
            acc[i][j] = (f32x4){0.f, 0.f, 0.f, 0.f};

    for (int k0 = 0; k0 < CD; k0 += 32) {
        long kb = (long)k0 * 2;
        #pragma unroll
        for (int c = 0; c < 2; ++c) {
            long rowoff = (long)(rb0 + c * 16) * 1024;
            long ldsoff = (long)(rb0 + c * 16) * 64;
            gload_lds16(gA_h + rowoff + kb + g_lane, ldsb + 0 * 8192 + ldsoff);
            gload_lds16(gA_l + rowoff + kb + g_lane, ldsb + 1 * 8192 + ldsoff);
            gload_lds16(gB_h + rowoff + kb + g_lane, ldsb + 2 * 8192 + ldsoff);
            gload_lds16(gB_l + rowoff + kb + g_lane, ldsb + 3 * 8192 + ldsoff);
        }
        asm volatile("s_waitcnt vmcnt(0)" ::: "memory");
        __syncthreads();

        half8 ah[4], al[4], bh[4], bl[4];
        #pragma unroll
        for (int i = 0; i < 4; ++i) {
            ah[i] = *(const half8*)(ldsb + 0 * 8192 + offA + i * 1024);
            al[i] = *(const half8*)(ldsb + 1 * 8192 + offA + i * 1024);
            bh[i] = *(const half8*)(ldsb + 2 * 8192 + offB + i * 1024);
            bl[i] = *(const half8*)(ldsb + 3 * 8192 + offB + i * 1024);
        }
        #pragma unroll
        for (int i = 0; i < 4; ++i)
            #pragma unroll
            for (int j = 0; j < 4; ++j) {
                acc[i][j] = __builtin_amdgcn_mfma_f32_16x16x32_f16(ah[i], bh[j], acc[i][j], 0, 0, 0);
                acc[i][j] = __builtin_amdgcn_mfma_f32_16x16x32_f16(ah[i], bl[j], acc[i][j], 0, 0, 0);
                acc[i][j] = __builtin_amdgcn_mfma_f32_16x16x32_f16(al[i], bh[j], acc[i][j], 0, 0, 0);
            }
        __syncthreads();
    }

    // C/D layout (m89-verified): col = lane&15, row = (lane>>4)*4 + reg
    float* outp = qkv + (long)b * OC3 * NN;
    int colb = n0 + wx * 64 + (lane & 15);
    int rowb = m0 + wy * 64 + ((lane >> 4) << 2);
    const float sc = 1.0f / 1024.0f;      // undo 64 * 16 scaling
    #pragma unroll
    for (int i = 0; i < 4; ++i)
        #pragma unroll
        for (int j = 0; j < 4; ++j)
            #pragma unroll
            for (int r = 0; r < 4; ++r)
                outp[(long)(rowb + i * 16 + r) * NN + colb + j * 16] = acc[i][j][r] * sc;
}

// ---------------------------------------------------------------------------
// fp32 GEMM with pre-transposed A:  C[M,N] = At^T @ B (+bias)   (for GEMM2)
// ---------------------------------------------------------------------------
__global__ __launch_bounds__(256) void gemm_t_kernel(
    const float* __restrict__ At, long sA, int ldA,
    const float* __restrict__ Bm, long sB, int ldB,
    float* __restrict__ Cm, long sC, int ldC,
    const float* __restrict__ bias,
    int K)
{
    int bz = blockIdx.z;
    At += (long)bz * sA;
    Bm += (long)bz * sB;
    Cm += (long)bz * sC;
    int m0 = blockIdx.y * 128, n0 = blockIdx.x * 128;

    __shared__ float As[16][128];
    __shared__ float Bs[16][128];

    int tx = threadIdx.x, ty = threadIdx.y;
    int t = ty * 16 + tx;
    int lk = t >> 5;
    int lc = t & 31;

    float acc[8][8] = {};

    for (int k0 = 0; k0 < K; k0 += 16) {
        #pragma unroll
        for (int i = 0; i < 2; ++i) {
            int kk = lk + i * 8;
            float4 va = *reinterpret_cast<const float4*>(&At[(long)(k0 + kk) * ldA + m0 + 4 * lc]);
            *reinterpret_cast<float4*>(&As[kk][4 * lc]) = va;
            float4 vb = *reinterpret_cast<const float4*>(&Bm[(long)(k0 + kk) * ldB + n0 + 4 * lc]);
            *reinterpret_cast<float4*>(&Bs[kk][4 * lc]) = vb;
        }
        __syncthreads();
        #pragma unroll
        for (int kk = 0; kk < 16; ++kk) {
            float a[8], bv[8];
            *reinterpret_cast<float4*>(&a[0]) = *reinterpret_cast<const float4*>(&As[kk][ty * 4]);
            *reinterpret_cast<float4*>(&a[4]) = *reinterpret_cast<const float4*>(&As[kk][64 + ty * 4]);
            *reinterpret_cast<float4*>(&bv[0]) = *reinterpret_cast<const float4*>(&Bs[kk][tx * 4]);
            *reinterpret_cast<float4*>(&bv[4]) = *reinterpret_cast<const float4*>(&Bs[kk][64 + tx * 4]);
            #pragma unroll
            for (int i = 0; i < 8; ++i)
                #pragma unroll
                for (int j = 0; j < 8; ++j)
                    acc[i][j] += a[i] * bv[j];
        }
        __syncthreads();
    }

    #pragma unroll
    for (int ih = 0; ih < 2; ++ih)
        #pragma unroll
        for (int i = 0; i < 4; ++i) {
            int row = m0 + ih * 64 + ty * 4 + i;
            float bb = bias ? bias[row] : 0.f;
            #pragma unroll
            for (int jh = 0; jh < 2; ++jh) {
                float4 o;
                o.x = acc[ih * 4 + i][jh * 4 + 0] + bb;
                o.y = acc[ih * 4 + i][jh * 4 + 1] + bb;
                o.z = acc[ih * 4 + i][jh * 4 + 2] + bb;
                o.w = acc[ih * 4 + i][jh * 4 + 3] + bb;
                *reinterpret_cast<float4*>(&Cm[(long)row * ldC + n0 + jh * 64 + tx * 4]) = o;
            }
        }
}

// ---------------------------------------------------------------------------
// q softmax over head_dim (axis d, 64 elems, stride NN), then * scale
// ---------------------------------------------------------------------------
__global__ __launch_bounds__(256) void softmax_q_kernel(float* __restrict__ qkv)
{
    long idx = (long)blockIdx.x * 256 + threadIdx.x;
    int n = (int)(idx & (NN - 1));
    long bh = idx >> 12;
    int h = (int)(bh & (HH - 1));
    int b = (int)(bh >> 3);
    float* base = qkv + ((long)b * OC3 + (long)h * DD) * NN + n;

    float v[DD];
    float mx = -INFINITY;
    #pragma unroll
    for (int d = 0; d < DD; ++d) {
        v[d] = base[(long)d * NN];
        mx = fmaxf(mx, v[d]);
    }
    float s = 0.f;
    #pragma unroll
    for (int d = 0; d < DD; ++d) {
        v[d] = expf(v[d] - mx);
        s += v[d];
    }
    float r = 0.125f / s;
    #pragma unroll
    for (int d = 0; d < DD; ++d)
        base[(long)d * NN] = v[d] * r;
}

// ---------------------------------------------------------------------------
// k softmax over tokens (axis n, 4096 contiguous). one block per row.
// ---------------------------------------------------------------------------
__global__ __launch_bounds__(256) void softmax_k_kernel(float* __restrict__ qkv)
{
    int row = blockIdx.x;
    int b = row >> 9;
    int hd = row & (CD - 1);
    float* base = qkv + ((long)b * OC3 + CD + hd) * NN;
    int t = threadIdx.x;

    float v[16];
    #pragma unroll
    for (int i = 0; i < 16; ++i) v[i] = base[t + i * 256];

    __shared__ float red[256];
    float mx = -INFINITY;
    #pragma unroll
    for (int i = 0; i < 16; ++i) mx = fmaxf(mx, v[i]);
    red[t] = mx; __syncthreads();
    for (int off = 128; off > 0; off >>= 1) {
        if (t < off) red[t] = fmaxf(red[t], red[t + off]);
        __syncthreads();
    }
    mx = red[0]; __syncthreads();

    float s = 0.f;
    #pragma unroll
    for (int i = 0; i < 16; ++i) {
        v[i] = expf(v[i] - mx);
        s += v[i];
    }
    red[t] = s; __syncthreads();
    for (int off = 128; off > 0; off >>= 1) {
        if (t < off) red[t] += red[t + off];
        __syncthreads();
    }
    float inv = 1.f / red[0];

    #pragma unroll
    for (int i = 0; i < 16; ++i) base[t + i * 256] = v[i] * inv;
}

// ---------------------------------------------------------------------------
// context partials: ctxp[bh][sp][d][e] = sum over n-slice of k_s[d,n]*v[e,n]
// ---------------------------------------------------------------------------
__global__ __launch_bounds__(256) void context_part_kernel(
    const float* __restrict__ qkv, float* __restrict__ ctxp)
{
    int bh = blockIdx.x;
    int sp = blockIdx.y;
    int b = bh >> 3, h = bh & 7;
    const float* kb = qkv + ((long)b * OC3 + CD + (long)h * DD) * NN;
    const float* vb = qkv + ((long)b * OC3 + 2 * CD + (long)h * DD) * NN;

    __shared__ float ks[64][65];
    __shared__ float vs[64][65];
    int tx = threadIdx.x, ty = threadIdx.y;
    int t = ty * 16 + tx;

    float acc[4][4] = {};

    int nbeg = sp * (NN / NSPLIT);
    for (int n0 = nbeg; n0 < nbeg + NN / NSPLIT; n0 += 64) {
        #pragma unroll
        for (int i = 0; i < 16; ++i) {
            int idx = t + i * 256;
            int r = idx >> 6, cc = idx & 63;
            ks[r][cc] = kb[(long)r * NN + n0 + cc];
            vs[r][cc] = vb[(long)r * NN + n0 + cc];
        }
        __syncthreads();
        #pragma unroll
        for (int nn = 0; nn < 64; ++nn) {
            float kd[4], vd[4];
            #pragma unroll
            for (int i = 0; i < 4; ++i) {
                kd[i] = ks[ty * 4 + i][nn];
                vd[i] = vs[tx * 4 + i][nn];
            }
            #pragma unroll
            for (int i = 0; i < 4; ++i)
                #pragma unroll
                for (int j = 0; j < 4; ++j)
                    acc[i][j] += kd[i] * vd[j];
        }
        __syncthreads();
    }

    #pragma unroll
    for (int i = 0; i < 4; ++i)
        #pragma unroll
        for (int j = 0; j < 4; ++j)
            ctxp[(((long)bh * NSPLIT + sp) * DD + ty * 4 + i) * DD + tx * 4 + j] = acc[i][j];
}

// ---------------------------------------------------------------------------
// reduce partials in fp64, apply 1/N
// ---------------------------------------------------------------------------
__global__ __launch_bounds__(256) void context_reduce_kernel(
    const float* __restrict__ ctxp, float* __restrict__ ctx)
{
    int idx = blockIdx.x * 256 + threadIdx.x;
    int bh = idx >> 12;
    int de = idx & 4095;
    double s = 0.0;
    #pragma unroll
    for (int sp = 0; sp < NSPLIT; ++sp)
        s += (double)ctxp[((long)bh * NSPLIT + sp) * 4096 + de];
    ctx[idx] = (float)(s * (1.0 / (double)NN));
}

// ---------------------------------------------------------------------------
// fold w_out into per-batch Mt: Mt[b][hd][c] = sum_e w_out[c][h*64+e]*ctx[..]
// ---------------------------------------------------------------------------
__global__ __launch_bounds__(256) void fold_wout_kernel(
    const float* __restrict__ w_out, const float* __restrict__ ctx,
    float* __restrict__ Mt)
{
    long idx = (long)blockIdx.x * 256 + threadIdx.x;
    int c  = (int)(idx & (CD - 1));
    int hd = (int)((idx >> 9) & (CD - 1));
    int b  = (int)(idx >> 18);
    int h = hd >> 6, d = hd & 63;
    const float* wrow = w_out + (long)c * CD + (long)h * DD;
    const float* crow = ctx + (((long)(b * HH + h) * DD + d) * DD);
    float s = 0.f;
    #pragma unroll
    for (int e = 0; e < DD; e += 4) {
        float4 wv = *reinterpret_cast<const float4*>(&wrow[e]);
        float4 cv = *reinterpret_cast<const float4*>(&crow[e]);
        s += wv.x * cv.x + wv.y * cv.y + wv.z * cv.z + wv.w * cv.w;
    }
    Mt[idx] = s;
}

// ---------------------------------------------------------------------------
// channel LayerNorm over c=512 (stride NN), fp64 stats; writes final output
// ---------------------------------------------------------------------------
__global__ __launch_bounds__(256) void layernorm_kernel(
    const float* __restrict__ qkv, const float* __restrict__ g,
    float* __restrict__ out)
{
    long idx = (long)blockIdx.x * 256 + threadIdx.x;
    int n = (int)(idx & (NN - 1));
    int b = (int)(idx >> 12);
    const float* col = qkv + (long)b * OC3 * NN + (long)CD * NN + n;

    double s = 0.0, ss = 0.0;
    for (int c = 0; c < CD; ++c) {
        float v = col[(long)c * NN];
        s += (double)v;
        ss += (double)v * (double)v;
    }
    double mean = s * (1.0 / CD);
    double var = ss * (1.0 / CD) - mean * mean;
    double inv = 1.0 / sqrt(var + 1e-5);
    float meanf = (float)mean, invf = (float)inv;

    float* ocol = out + (long)b * CD * NN + n;
    for (int c = 0; c < CD; ++c)
        ocol[(long)c * NN] = (col[(long)c * NN] - meanf) * invf * g[c];
}

// ---------------------------------------------------------------------------
extern "C" void kernel_launch(void* const* d_in, const int* in_sizes, int n_in,
                              void* d_out, int out_size, void* d_ws, size_t ws_size,
                              hipStream_t stream)
{
    const float* x     = (const float*)d_in[0];
    const float* w_qkv = (const float*)d_in[1];
    const float* w_out = (const float*)d_in[2];
    const float* b_out = (const float*)d_in[3];
    const float* g     = (const float*)d_in[4];
    float* out = (float*)d_out;

    float* ws   = (float*)d_ws;
    float* qkv  = ws;                                      // 50,331,648 f
    float* ctxp = qkv + (long)BB * OC3 * NN;               //  4,194,304 f
    float* ctx  = ctxp + (long)BB * HH * NSPLIT * DD * DD; //    262,144 f
    float* Mt   = ctx + (long)BB * HH * DD * DD;           //  2,097,152 f
    f16*   wh   = (f16*)(Mt + (long)BB * CD * CD);         //    786,432 h
    f16*   wl   = wh + (long)OC3 * CD;                     //    786,432 h

    // x split/transpose scratch lives in d_out (dead before LN writes it):
    // xth + xtl = 2 * 16,777,216 f16 = 67.1 MB = exactly out_size
    f16* xth = (f16*)d_out;
    f16* xtl = xth + (long)BB * NN * CD;

    // 0) operand splits
    split_w_kernel<<<(OC3 * CD / 4) / 256, 256, 0, stream>>>(w_qkv, wh, wl);
    split_x_kernel<<<dim3(NN / 32, CD / 32, BB), dim3(32, 8), 0, stream>>>(x, xth, xtl);

    // 1) qkv = w_qkv @ x  via split-f16 MFMA
    qkv_mfma_kernel<<<dim3(NN / 128, OC3 / 128, BB), 256, 0, stream>>>(
        wh, wl, xth, xtl, qkv);

    // 2) softmaxes (in place)
    softmax_q_kernel<<<(BB * HH * NN) / 256, 256, 0, stream>>>(qkv);
    softmax_k_kernel<<<BB * CD, 256, 0, stream>>>(qkv);

    // 3) context = k_s @ v^T / N
    context_part_kernel<<<dim3(BB * HH, NSPLIT), dim3(16, 16), 0, stream>>>(qkv, ctxp);
    context_reduce_kernel<<<(BB * HH * DD * DD) / 256, 256, 0, stream>>>(ctxp, ctx);

    // 4) Mt = fold(w_out, ctx)
    fold_wout_kernel<<<(BB * CD * CD) / 256, 256, 0, stream>>>(w_out, ctx, Mt);

    // 5) y = M_b @ q_s + b_out  (fp32, precision-critical) -> dead k_s region
    gemm_t_kernel<<<dim3(NN / 128, CD / 128, BB), dim3(16, 16), 0, stream>>>(
        Mt, (long)CD * CD, CD,
        qkv, (long)OC3 * NN, NN,
        qkv + (long)CD * NN, (long)OC3 * NN, NN,
        b_out, CD);

    // 6) channel LayerNorm -> d_out (overwrites xth/xtl scratch)
    layernorm_kernel<<<(BB * NN) / 256, 256, 0, stream>>>(qkv, g, out);
}

// Round 4
// 566.670 us; speedup vs baseline: 2.2755x; 1.0877x over previous
//
#include <hip/hip_runtime.h>
#include <math.h>

// Problem constants
#define BB 8
#define NN 4096      // 64*64 tokens
#define CD 512       // channels
#define HH 8
#define DD 64
#define OC3 1536     // 3*hidden
#define NSPLIT 16

typedef _Float16 f16;
typedef _Float16 half8 __attribute__((ext_vector_type(8)));
typedef _Float16 half4v __attribute__((ext_vector_type(4)));
typedef float f32x4 __attribute__((ext_vector_type(4)));

__device__ __forceinline__ void gload_lds16(const void* g, void* l) {
    __builtin_amdgcn_global_load_lds(
        (const __attribute__((address_space(1))) unsigned int*)g,
        (__attribute__((address_space(3))) unsigned int*)l, 16, 0, 0);
}

// ---------------------------------------------------------------------------
// split w_qkv [1536][512] f32 -> wh, wl [1536][512] f16, scaled by 64
// ---------------------------------------------------------------------------
__global__ __launch_bounds__(256) void split_w_kernel(
    const float* __restrict__ w, f16* __restrict__ wh, f16* __restrict__ wl)
{
    int idx = blockIdx.x * 256 + threadIdx.x;      // OC3*CD/4 = 196608 total
    float4 v = ((const float4*)w)[idx];
    float a[4] = {v.x, v.y, v.z, v.w};
    half4v h, l;
    #pragma unroll
    for (int i = 0; i < 4; ++i) {
        float s = a[i] * 64.f;
        f16 hh = (f16)s;
        h[i] = hh;
        l[i] = (f16)(s - (float)hh);
    }
    *(half4v*)(&wh[(long)idx * 4]) = h;
    *(half4v*)(&wl[(long)idx * 4]) = l;
}

// ---------------------------------------------------------------------------
// split + transpose x [b][512 k][4096 n] f32 -> xth, xtl [b][4096 n][512 k]
// f16, scaled by 16.  block (32,8), 32x32 tile.
// ---------------------------------------------------------------------------
__global__ __launch_bounds__(256) void split_x_kernel(
    const float* __restrict__ x, f16* __restrict__ xth, f16* __restrict__ xtl)
{
    __shared__ float tile[32][33];
    int b = blockIdx.z;
    int n0 = blockIdx.x * 32, k0 = blockIdx.y * 32;
    const float* xb = x + (long)b * CD * NN;
    int tx = threadIdx.x, ty = threadIdx.y;
    #pragma unroll
    for (int i = 0; i < 4; ++i)
        tile[ty + i * 8][tx] = xb[(long)(k0 + ty + i * 8) * NN + n0 + tx];
    __syncthreads();
    long obase = (long)b * NN * CD;
    #pragma unroll
    for (int i = 0; i < 4; ++i) {
        int n = n0 + ty + i * 8;
        float s = tile[tx][ty + i * 8] * 16.f;
        f16 h = (f16)s;
        f16 l = (f16)(s - (float)h);
        xth[obase + (long)n * CD + k0 + tx] = h;
        xtl[obase + (long)n * CD + k0 + tx] = l;
    }
}

// ---------------------------------------------------------------------------
// Shared split-f16 MFMA GEMM, K=512 fixed.
// C[M,N] = (Ah+Al)^T-free: A [M][512] f16 h/l, B [N][512] f16 h/l,
// 3 products hh+hl+lh, fp32 accum. Batched via grid.z with element strides.
// Block 256 (4 waves 2x2), tile 128x128, wave 64x64, KT=32,
// mfma_f32_16x16x32_f16. LDS XOR chunk-swizzle staging via global_load_lds
// (linear dest + inv-swizzled global source + swizzled read).
// Epilogue: C = acc * base_sc * (inv_sc ? inv_sc[bz] : 1) + bias[row]
// ---------------------------------------------------------------------------
__global__ __launch_bounds__(256) void mfma_gemm_kernel(
    const f16* __restrict__ Ah, const f16* __restrict__ Al, long sA,
    const f16* __restrict__ Bh, const f16* __restrict__ Bl, long sB,
    float* __restrict__ Cp, long sC, int ldC,
    const float* __restrict__ bias, const float* __restrict__ inv_sc,
    float base_sc)
{
    __shared__ f16 lds[4][128 * 32];     // Ah, Al, Bh, Bl ; 8 KB each
    int bz = blockIdx.z;
    int n0 = blockIdx.x * 128, m0 = blockIdx.y * 128;
    int t = threadIdx.x;
    int lane = t & 63, wid = t >> 6;
    int wy = wid >> 1, wx = wid & 1;

    // staging: physical chunk = lane&3, logical chunk = (lane&3)^((row>>1)&3)
    int cl = (lane & 3) ^ ((lane >> 3) & 3);
    long g_lane = (long)(lane >> 2) * 1024 + (long)cl * 16;   // bytes; row = K=512 f16 = 1024 B

    const char* gA_h = (const char*)(Ah + bz * sA) + (long)m0 * 1024;
    const char* gA_l = (const char*)(Al + bz * sA) + (long)m0 * 1024;
    const char* gB_h = (const char*)(Bh + bz * sB) + (long)n0 * 1024;
    const char* gB_l = (const char*)(Bl + bz * sB) + (long)n0 * 1024;

    char* ldsb = (char*)&lds[0][0];
    int rb0 = wid * 32;                  // this wave stages rows rb0..rb0+31

    // frag read: want logical chunk (lane>>4); read physical
    int cp = (lane >> 4) ^ (((lane & 15) >> 1) & 3);
    long offA = (long)(wy * 64 + (lane & 15)) * 64 + (long)cp * 16;
    long offB = (long)(wx * 64 + (lane & 15)) * 64 + (long)cp * 16;

    f32x4 acc[4][4];
    #pragma unroll
    for (int i = 0; i < 4; ++i)
        #pragma unroll
        for (int j = 0; j < 4; ++j)
            acc[i][j] = (f32x4){0.f, 0.f, 0.f, 0.f};

    for (int k0 = 0; k0 < CD; k0 += 32) {
        long kb = (long)k0 * 2;
        #pragma unroll
        for (int c = 0; c < 2; ++c) {
            long rowoff = (long)(rb0 + c * 16) * 1024;
            long ldsoff = (long)(rb0 + c * 16) * 64;
            gload_lds16(gA_h + rowoff + kb + g_lane, ldsb + 0 * 8192 + ldsoff);
            gload_lds16(gA_l + rowoff + kb + g_lane, ldsb + 1 * 8192 + ldsoff);
            gload_lds16(gB_h + rowoff + kb + g_lane, ldsb + 2 * 8192 + ldsoff);
            gload_lds16(gB_l + rowoff + kb + g_lane, ldsb + 3 * 8192 + ldsoff);
        }
        asm volatile("s_waitcnt vmcnt(0)" ::: "memory");
        __syncthreads();

        half8 ah[4], al[4], bh[4], bl[4];
        #pragma unroll
        for (int i = 0; i < 4; ++i) {
            ah[i] = *(const half8*)(ldsb + 0 * 8192 + offA + i * 1024);
            al[i] = *(const half8*)(ldsb + 1 * 8192 + offA + i * 1024);
            bh[i] = *(const half8*)(ldsb + 2 * 8192 + offB + i * 1024);
            bl[i] = *(const half8*)(ldsb + 3 * 8192 + offB + i * 1024);
        }
        #pragma unroll
        for (int i = 0; i < 4; ++i)
            #pragma unroll
            for (int j = 0; j < 4; ++j) {
                acc[i][j] = __builtin_amdgcn_mfma_f32_16x16x32_f16(ah[i], bh[j], acc[i][j], 0, 0, 0);
                acc[i][j] = __builtin_amdgcn_mfma_f32_16x16x32_f16(ah[i], bl[j], acc[i][j], 0, 0, 0);
                acc[i][j] = __builtin_amdgcn_mfma_f32_16x16x32_f16(al[i], bh[j], acc[i][j], 0, 0, 0);
            }
        __syncthreads();
    }

    // C/D layout: col = lane&15, row = (lane>>4)*4 + reg
    float* outp = Cp + bz * sC;
    int colb = n0 + wx * 64 + (lane & 15);
    int rowb = m0 + wy * 64 + ((lane >> 4) << 2);
    float mult = base_sc * (inv_sc ? inv_sc[bz] : 1.f);
    #pragma unroll
    for (int i = 0; i < 4; ++i)
        #pragma unroll
        for (int j = 0; j < 4; ++j)
            #pragma unroll
            for (int r = 0; r < 4; ++r) {
                int row = rowb + i * 16 + r;
                float bb = bias ? bias[row] : 0.f;
                outp[(long)row * ldC + colb + j * 16] = acc[i][j][r] * mult + bb;
            }
}

// ---------------------------------------------------------------------------
// q softmax over head_dim (strided read), emit split-f16 TRANSPOSED:
// qth/qtl [b][n][512], values = p * 32 (= q_s * 256)
// ---------------------------------------------------------------------------
__global__ __launch_bounds__(256) void softmax_q_kernel(
    const float* __restrict__ qkv, f16* __restrict__ qth, f16* __restrict__ qtl)
{
    long idx = (long)blockIdx.x * 256 + threadIdx.x;   // B*H*N total
    int n = (int)(idx & (NN - 1));
    long bh = idx >> 12;
    int h = (int)(bh & (HH - 1));
    int b = (int)(bh >> 3);
    const float* base = qkv + ((long)b * OC3 + (long)h * DD) * NN + n;

    float v[DD];
    float mx = -INFINITY;
    #pragma unroll
    for (int d = 0; d < DD; ++d) {
        v[d] = base[(long)d * NN];
        mx = fmaxf(mx, v[d]);
    }
    float s = 0.f;
    #pragma unroll
    for (int d = 0; d < DD; ++d) {
        v[d] = expf(v[d] - mx);
        s += v[d];
    }
    float r = 32.f / s;     // p * 32 == q_s * 256

    long obase = ((long)b * NN + n) * CD + (long)h * DD;
    #pragma unroll
    for (int d0 = 0; d0 < DD; d0 += 8) {
        half8 hh, ll;
        #pragma unroll
        for (int j = 0; j < 8; ++j) {
            float tval = v[d0 + j] * r;
            f16 hv = (f16)tval;
            hh[j] = hv;
            ll[j] = (f16)(tval - (float)hv);
        }
        *(half8*)(&qth[obase + d0]) = hh;
        *(half8*)(&qtl[obase + d0]) = ll;
    }
}

// ---------------------------------------------------------------------------
// k softmax over tokens (axis n, 4096 contiguous). one block per row.
// ---------------------------------------------------------------------------
__global__ __launch_bounds__(256) void softmax_k_kernel(float* __restrict__ qkv)
{
    int row = blockIdx.x;
    int b = row >> 9;
    int hd = row & (CD - 1);
    float* base = qkv + ((long)b * OC3 + CD + hd) * NN;
    int t = threadIdx.x;

    float v[16];
    #pragma unroll
    for (int i = 0; i < 16; ++i) v[i] = base[t + i * 256];

    __shared__ float red[256];
    float mx = -INFINITY;
    #pragma unroll
    for (int i = 0; i < 16; ++i) mx = fmaxf(mx, v[i]);
    red[t] = mx; __syncthreads();
    for (int off = 128; off > 0; off >>= 1) {
        if (t < off) red[t] = fmaxf(red[t], red[t + off]);
        __syncthreads();
    }
    mx = red[0]; __syncthreads();

    float s = 0.f;
    #pragma unroll
    for (int i = 0; i < 16; ++i) {
        v[i] = expf(v[i] - mx);
        s += v[i];
    }
    red[t] = s; __syncthreads();
    for (int off = 128; off > 0; off >>= 1) {
        if (t < off) red[t] += red[t + off];
        __syncthreads();
    }
    float inv = 1.f / red[0];

    #pragma unroll
    for (int i = 0; i < 16; ++i) base[t + i * 256] = v[i] * inv;
}

// ---------------------------------------------------------------------------
// context partials: ctxp[bh][sp][d][e] = sum over n-slice of k_s[d,n]*v[e,n]
// ---------------------------------------------------------------------------
__global__ __launch_bounds__(256) void context_part_kernel(
    const float* __restrict__ qkv, float* __restrict__ ctxp)
{
    int bh = blockIdx.x;
    int sp = blockIdx.y;
    int b = bh >> 3, h = bh & 7;
    const float* kb = qkv + ((long)b * OC3 + CD + (long)h * DD) * NN;
    const float* vb = qkv + ((long)b * OC3 + 2 * CD + (long)h * DD) * NN;

    __shared__ float ks[64][65];
    __shared__ float vs[64][65];
    int tx = threadIdx.x, ty = threadIdx.y;
    int t = ty * 16 + tx;

    float acc[4][4] = {};

    int nbeg = sp * (NN / NSPLIT);
    for (int n0 = nbeg; n0 < nbeg + NN / NSPLIT; n0 += 64) {
        #pragma unroll
        for (int i = 0; i < 16; ++i) {
            int idx = t + i * 256;
            int r = idx >> 6, cc = idx & 63;
            ks[r][cc] = kb[(long)r * NN + n0 + cc];
            vs[r][cc] = vb[(long)r * NN + n0 + cc];
        }
        __syncthreads();
        #pragma unroll
        for (int nn = 0; nn < 64; ++nn) {
            float kd[4], vd[4];
            #pragma unroll
            for (int i = 0; i < 4; ++i) {
                kd[i] = ks[ty * 4 + i][nn];
                vd[i] = vs[tx * 4 + i][nn];
            }
            #pragma unroll
            for (int i = 0; i < 4; ++i)
                #pragma unroll
                for (int j = 0; j < 4; ++j)
                    acc[i][j] += kd[i] * vd[j];
        }
        __syncthreads();
    }

    #pragma unroll
    for (int i = 0; i < 4; ++i)
        #pragma unroll
        for (int j = 0; j < 4; ++j)
            ctxp[(((long)bh * NSPLIT + sp) * DD + ty * 4 + i) * DD + tx * 4 + j] = acc[i][j];
}

// ---------------------------------------------------------------------------
// reduce partials in fp64, apply 1/N
// ---------------------------------------------------------------------------
__global__ __launch_bounds__(256) void context_reduce_kernel(
    const float* __restrict__ ctxp, float* __restrict__ ctx)
{
    int idx = blockIdx.x * 256 + threadIdx.x;
    int bh = idx >> 12;
    int de = idx & 4095;
    double s = 0.0;
    #pragma unroll
    for (int sp = 0; sp < NSPLIT; ++sp)
        s += (double)ctxp[((long)bh * NSPLIT + sp) * 4096 + de];
    ctx[idx] = (float)(s * (1.0 / (double)NN));
}

// ---------------------------------------------------------------------------
// fold w_out into per-batch M (row-major [c][hd], hd fast -> coalesced):
//   M[b][c][hd] = sum_e w_out[c][h*64+e] * ctx[b,h,d,e],  hd = h*64+d
// ---------------------------------------------------------------------------
__global__ __launch_bounds__(256) void fold_wout_kernel(
    const float* __restrict__ w_out, const float* __restrict__ ctx,
    float* __restrict__ Mf)
{
    long idx = (long)blockIdx.x * 256 + threadIdx.x;   // B*512*512
    int hd = (int)(idx & (CD - 1));
    int c  = (int)((idx >> 9) & (CD - 1));
    int b  = (int)(idx >> 18);
    int h = hd >> 6, d = hd & 63;
    const float* wrow = w_out + (long)c * CD + (long)h * DD;
    const float* crow = ctx + (((long)(b * HH + h) * DD + d) * DD);
    float s = 0.f;
    #pragma unroll
    for (int e = 0; e < DD; e += 4) {
        float4 wv = *reinterpret_cast<const float4*>(&wrow[e]);
        float4 cv = *reinterpret_cast<const float4*>(&crow[e]);
        s += wv.x * cv.x + wv.y * cv.y + wv.z * cv.z + wv.w * cv.w;
    }
    Mf[idx] = s;
}

// ---------------------------------------------------------------------------
// per-batch max|M| -> power-of-2 scale (max*scale in [1024,2048))
// scl[b] = scale, scl[8+b] = 1/scale
// ---------------------------------------------------------------------------
__global__ __launch_bounds__(256) void max_m_kernel(
    const float* __restrict__ Mf, float* __restrict__ scl)
{
    int b = blockIdx.x;
    const float4* p = (const float4*)(Mf + (long)b * CD * CD);
    float mx = 0.f;
    for (int i = threadIdx.x; i < CD * CD / 4; i += 256) {
        float4 v = p[i];
        mx = fmaxf(mx, fmaxf(fmaxf(fabsf(v.x), fabsf(v.y)),
                             fmaxf(fabsf(v.z), fabsf(v.w))));
    }
    __shared__ float red[256];
    red[threadIdx.x] = mx; __syncthreads();
    for (int off = 128; off > 0; off >>= 1) {
        if (threadIdx.x < off) red[threadIdx.x] = fmaxf(red[threadIdx.x], red[threadIdx.x + off]);
        __syncthreads();
    }
    if (threadIdx.x == 0) {
        float m = red[0];
        int e = (m > 1e-30f) ? ilogbf(m) : 0;
        scl[b] = ldexpf(1.f, 10 - e);
        scl[8 + b] = ldexpf(1.f, e - 10);
    }
}

// ---------------------------------------------------------------------------
// split M fp32 -> mh/ml f16 with per-batch scale
// ---------------------------------------------------------------------------
__global__ __launch_bounds__(256) void split_m_kernel(
    const float* __restrict__ Mf, const float* __restrict__ scl,
    f16* __restrict__ mh, f16* __restrict__ ml)
{
    int idx = blockIdx.x * 256 + threadIdx.x;   // BB*CD*CD/4 = 524288 float4s
    float s = scl[idx >> 16];                   // 65536 float4s per batch
    float4 v = ((const float4*)Mf)[idx];
    float a[4] = {v.x, v.y, v.z, v.w};
    half4v h, l;
    #pragma unroll
    for (int i = 0; i < 4; ++i) {
        float tval = a[i] * s;
        f16 hv = (f16)tval;
        h[i] = hv;
        l[i] = (f16)(tval - (float)hv);
    }
    *(half4v*)(&mh[(long)idx * 4]) = h;
    *(half4v*)(&ml[(long)idx * 4]) = l;
}

// ---------------------------------------------------------------------------
// channel LayerNorm over c=512 (stride NN), fp64 stats; writes final output
// ---------------------------------------------------------------------------
__global__ __launch_bounds__(256) void layernorm_kernel(
    const float* __restrict__ qkv, const float* __restrict__ g,
    float* __restrict__ out)
{
    long idx = (long)blockIdx.x * 256 + threadIdx.x;
    int n = (int)(idx & (NN - 1));
    int b = (int)(idx >> 12);
    const float* col = qkv + (long)b * OC3 * NN + (long)CD * NN + n;

    double s = 0.0, ss = 0.0;
    for (int c = 0; c < CD; ++c) {
        float v = col[(long)c * NN];
        s += (double)v;
        ss += (double)v * (double)v;
    }
    double mean = s * (1.0 / CD);
    double var = ss * (1.0 / CD) - mean * mean;
    double inv = 1.0 / sqrt(var + 1e-5);
    float meanf = (float)mean, invf = (float)inv;

    float* ocol = out + (long)b * CD * NN + n;
    for (int c = 0; c < CD; ++c)
        ocol[(long)c * NN] = (col[(long)c * NN] - meanf) * invf * g[c];
}

// ---------------------------------------------------------------------------
extern "C" void kernel_launch(void* const* d_in, const int* in_sizes, int n_in,
                              void* d_out, int out_size, void* d_ws, size_t ws_size,
                              hipStream_t stream)
{
    const float* x     = (const float*)d_in[0];
    const float* w_qkv = (const float*)d_in[1];
    const float* w_out = (const float*)d_in[2];
    const float* b_out = (const float*)d_in[3];
    const float* g     = (const float*)d_in[4];
    float* out = (float*)d_out;

    float* ws   = (float*)d_ws;
    float* qkv  = ws;                                      // 50,331,648 f
    float* ctxp = qkv + (long)BB * OC3 * NN;               //  4,194,304 f (reused for Mf)
    float* ctx  = ctxp + (long)BB * HH * NSPLIT * DD * DD; //    262,144 f
    f16*   mh   = (f16*)(ctx + (long)BB * HH * DD * DD);   //  2,097,152 h
    f16*   ml   = mh + (long)BB * CD * CD;                 //  2,097,152 h
    f16*   wh   = (f16*)(ml + (long)BB * CD * CD);         //    786,432 h
    f16*   wl   = wh + (long)OC3 * CD;                     //    786,432 h
    float* scl  = (float*)(wl + (long)OC3 * CD);           //         16 f
    float* Mf   = ctxp;                                    // 2,097,152 f (ctxp dead)

    // d_out as scratch: xth/xtl (phase 1), then qth/qtl (phase 2); LN
    // overwrites at the end. 2 * 16,777,216 f16 = 67.1 MB = out_size exactly.
    f16* xth = (f16*)d_out;
    f16* xtl = xth + (long)BB * NN * CD;
    f16* qth = xth;    // reuse after qkv_mfma consumed xth/xtl
    f16* qtl = xtl;

    // 0) operand splits
    split_w_kernel<<<(OC3 * CD / 4) / 256, 256, 0, stream>>>(w_qkv, wh, wl);
    split_x_kernel<<<dim3(NN / 32, CD / 32, BB), dim3(32, 8), 0, stream>>>(x, xth, xtl);

    // 1) qkv = w_qkv @ x  via split-f16 MFMA  (undo 64*16 scaling)
    mfma_gemm_kernel<<<dim3(NN / 128, OC3 / 128, BB), 256, 0, stream>>>(
        wh, wl, 0L, xth, xtl, (long)NN * CD,
        qkv, (long)OC3 * NN, NN, nullptr, nullptr, 1.0f / 1024.0f);

    // 2) softmaxes: q -> split-f16 transposed (overwrites x scratch), k in place
    softmax_q_kernel<<<(BB * HH * NN) / 256, 256, 0, stream>>>(qkv, qth, qtl);
    softmax_k_kernel<<<BB * CD, 256, 0, stream>>>(qkv);

    // 3) context = k_s @ (v/N)^T
    context_part_kernel<<<dim3(BB * HH, NSPLIT), dim3(16, 16), 0, stream>>>(qkv, ctxp);
    context_reduce_kernel<<<(BB * HH * DD * DD) / 256, 256, 0, stream>>>(ctxp, ctx);

    // 4) M = fold(w_out, ctx) fp32 -> dynamic per-batch pow2 scale -> f16 split
    fold_wout_kernel<<<(BB * CD * CD) / 256, 256, 0, stream>>>(w_out, ctx, Mf);
    max_m_kernel<<<BB, 256, 0, stream>>>(Mf, scl);
    split_m_kernel<<<(BB * CD * CD / 4) / 256, 256, 0, stream>>>(Mf, scl, mh, ml);

    // 5) y = M_b @ q_s + b_out via split-f16 MFMA -> dead k_s region of qkv
    //    multiplier = (1/256) * (1/scale_m[b])   (q stored as q_s*256)
    mfma_gemm_kernel<<<dim3(NN / 128, CD / 128, BB), 256, 0, stream>>>(
        mh, ml, (long)CD * CD, qth, qtl, (long)NN * CD,
        qkv + (long)CD * NN, (long)OC3 * NN, NN, b_out, scl + 8, 1.0f / 256.0f);

    // 6) channel LayerNorm -> d_out (overwrites q scratch)
    layernorm_kernel<<<(BB * NN) / 256, 256, 0, stream>>>(qkv, g, out);
}

// Round 5
// 526.966 us; speedup vs baseline: 2.4469x; 1.0753x over previous
//
#include <hip/hip_runtime.h>
#include <math.h>

// Problem constants
#define BB 8
#define NN 4096      // 64*64 tokens
#define CD 512       // channels
#define HH 8
#define DD 64
#define OC3 1536     // 3*hidden
#define NSPLIT 16

typedef _Float16 f16;
typedef _Float16 half8 __attribute__((ext_vector_type(8)));
typedef _Float16 half4v __attribute__((ext_vector_type(4)));
typedef float f32x4 __attribute__((ext_vector_type(4)));

__device__ __forceinline__ void gload_lds16(const void* g, void* l) {
    __builtin_amdgcn_global_load_lds(
        (const __attribute__((address_space(1))) unsigned int*)g,
        (__attribute__((address_space(3))) unsigned int*)l, 16, 0, 0);
}

// ---------------------------------------------------------------------------
// split w_qkv [1536][512] f32 -> wh, wl [1536][512] f16, scaled by 64
// ---------------------------------------------------------------------------
__global__ __launch_bounds__(256) void split_w_kernel(
    const float* __restrict__ w, f16* __restrict__ wh, f16* __restrict__ wl)
{
    int idx = blockIdx.x * 256 + threadIdx.x;      // OC3*CD/4 = 196608 total
    float4 v = ((const float4*)w)[idx];
    float a[4] = {v.x, v.y, v.z, v.w};
    half4v h, l;
    #pragma unroll
    for (int i = 0; i < 4; ++i) {
        float s = a[i] * 64.f;
        f16 hh = (f16)s;
        h[i] = hh;
        l[i] = (f16)(s - (float)hh);
    }
    *(half4v*)(&wh[(long)idx * 4]) = h;
    *(half4v*)(&wl[(long)idx * 4]) = l;
}

// ---------------------------------------------------------------------------
// split + transpose x [b][512 k][4096 n] f32 -> xth, xtl [b][4096 n][512 k]
// f16, scaled by 16.  block (32,8), 32x32 tile.
// ---------------------------------------------------------------------------
__global__ __launch_bounds__(256) void split_x_kernel(
    const float* __restrict__ x, f16* __restrict__ xth, f16* __restrict__ xtl)
{
    __shared__ float tile[32][33];
    int b = blockIdx.z;
    int n0 = blockIdx.x * 32, k0 = blockIdx.y * 32;
    const float* xb = x + (long)b * CD * NN;
    int tx = threadIdx.x, ty = threadIdx.y;
    #pragma unroll
    for (int i = 0; i < 4; ++i)
        tile[ty + i * 8][tx] = xb[(long)(k0 + ty + i * 8) * NN + n0 + tx];
    __syncthreads();
    long obase = (long)b * NN * CD;
    #pragma unroll
    for (int i = 0; i < 4; ++i) {
        int n = n0 + ty + i * 8;
        float s = tile[tx][ty + i * 8] * 16.f;
        f16 h = (f16)s;
        f16 l = (f16)(s - (float)h);
        xth[obase + (long)n * CD + k0 + tx] = h;
        xtl[obase + (long)n * CD + k0 + tx] = l;
    }
}

// ---------------------------------------------------------------------------
// Shared split-f16 MFMA GEMM, K=512 fixed. 3 products hh+hl+lh, fp32 accum.
// Block 256 (4 waves 2x2), tile 128x128, wave 64x64, KT=32.
// If vout != nullptr: blocks with m0 >= 1024 (the v third of qkv) write
// split-f16 v (scale x16) into the v region instead of fp32.
// ---------------------------------------------------------------------------
__global__ __launch_bounds__(256) void mfma_gemm_kernel(
    const f16* __restrict__ Ah, const f16* __restrict__ Al, long sA,
    const f16* __restrict__ Bh, const f16* __restrict__ Bl, long sB,
    float* __restrict__ Cp, long sC, int ldC,
    const float* __restrict__ bias, const float* __restrict__ inv_sc,
    float base_sc, f16* __restrict__ vout)
{
    __shared__ f16 lds[4][128 * 32];     // Ah, Al, Bh, Bl ; 8 KB each
    int bz = blockIdx.z;
    int n0 = blockIdx.x * 128, m0 = blockIdx.y * 128;
    int t = threadIdx.x;
    int lane = t & 63, wid = t >> 6;
    int wy = wid >> 1, wx = wid & 1;

    // staging: physical chunk = lane&3, logical chunk = (lane&3)^((row>>1)&3)
    int cl = (lane & 3) ^ ((lane >> 3) & 3);
    long g_lane = (long)(lane >> 2) * 1024 + (long)cl * 16;   // row = 512 f16 = 1024 B

    const char* gA_h = (const char*)(Ah + bz * sA) + (long)m0 * 1024;
    const char* gA_l = (const char*)(Al + bz * sA) + (long)m0 * 1024;
    const char* gB_h = (const char*)(Bh + bz * sB) + (long)n0 * 1024;
    const char* gB_l = (const char*)(Bl + bz * sB) + (long)n0 * 1024;

    char* ldsb = (char*)&lds[0][0];
    int rb0 = wid * 32;                  // this wave stages rows rb0..rb0+31

    // frag read: want logical chunk (lane>>4); read physical
    int cp = (lane >> 4) ^ (((lane & 15) >> 1) & 3);
    long offA = (long)(wy * 64 + (lane & 15)) * 64 + (long)cp * 16;
    long offB = (long)(wx * 64 + (lane & 15)) * 64 + (long)cp * 16;

    f32x4 acc[4][4];
    #pragma unroll
    for (int i = 0; i < 4; ++i)
        #pragma unroll
        for (int j = 0; j < 4; ++j)
            acc[i][j] = (f32x4){0.f, 0.f, 0.f, 0.f};

    for (int k0 = 0; k0 < CD; k0 += 32) {
        long kb = (long)k0 * 2;
        #pragma unroll
        for (int c = 0; c < 2; ++c) {
            long rowoff = (long)(rb0 + c * 16) * 1024;
            long ldsoff = (long)(rb0 + c * 16) * 64;
            gload_lds16(gA_h + rowoff + kb + g_lane, ldsb + 0 * 8192 + ldsoff);
            gload_lds16(gA_l + rowoff + kb + g_lane, ldsb + 1 * 8192 + ldsoff);
            gload_lds16(gB_h + rowoff + kb + g_lane, ldsb + 2 * 8192 + ldsoff);
            gload_lds16(gB_l + rowoff + kb + g_lane, ldsb + 3 * 8192 + ldsoff);
        }
        asm volatile("s_waitcnt vmcnt(0)" ::: "memory");
        __syncthreads();

        half8 ah[4], al[4], bh[4], bl[4];
        #pragma unroll
        for (int i = 0; i < 4; ++i) {
            ah[i] = *(const half8*)(ldsb + 0 * 8192 + offA + i * 1024);
            al[i] = *(const half8*)(ldsb + 1 * 8192 + offA + i * 1024);
            bh[i] = *(const half8*)(ldsb + 2 * 8192 + offB + i * 1024);
            bl[i] = *(const half8*)(ldsb + 3 * 8192 + offB + i * 1024);
        }
        #pragma unroll
        for (int i = 0; i < 4; ++i)
            #pragma unroll
            for (int j = 0; j < 4; ++j) {
                acc[i][j] = __builtin_amdgcn_mfma_f32_16x16x32_f16(ah[i], bh[j], acc[i][j], 0, 0, 0);
                acc[i][j] = __builtin_amdgcn_mfma_f32_16x16x32_f16(ah[i], bl[j], acc[i][j], 0, 0, 0);
                acc[i][j] = __builtin_amdgcn_mfma_f32_16x16x32_f16(al[i], bh[j], acc[i][j], 0, 0, 0);
            }
        __syncthreads();
    }

    // C/D layout: col = lane&15, row = (lane>>4)*4 + reg
    int colb = n0 + wx * 64 + (lane & 15);
    int rowb = m0 + wy * 64 + ((lane >> 4) << 2);

    if (vout && m0 >= 1024) {
        // v third: emit split-f16 (value = v_true * 16) into qkv's v region
        long vbase2 = 2L * ((long)bz * OC3 * NN + 2L * CD * NN);
        f16* vhp = vout + vbase2;
        f16* vlp = vhp + (long)CD * NN;
        float vsc = base_sc * 16.f;
        #pragma unroll
        for (int i = 0; i < 4; ++i)
            #pragma unroll
            for (int j = 0; j < 4; ++j)
                #pragma unroll
                for (int r = 0; r < 4; ++r) {
                    long row = rowb + i * 16 + r - 1024;
                    float val = acc[i][j][r] * vsc;
                    f16 hv = (f16)val;
                    vhp[row * NN + colb + j * 16] = hv;
                    vlp[row * NN + colb + j * 16] = (f16)(val - (float)hv);
                }
        return;
    }

    float* outp = Cp + bz * sC;
    float mult = base_sc * (inv_sc ? inv_sc[bz] : 1.f);
    #pragma unroll
    for (int i = 0; i < 4; ++i)
        #pragma unroll
        for (int j = 0; j < 4; ++j)
            #pragma unroll
            for (int r = 0; r < 4; ++r) {
                int row = rowb + i * 16 + r;
                float bb = bias ? bias[row] : 0.f;
                outp[(long)row * ldC + colb + j * 16] = acc[i][j][r] * mult + bb;
            }
}

// ---------------------------------------------------------------------------
// q softmax over head_dim (strided read), emit split-f16 TRANSPOSED:
// qth/qtl [b][n][512], values = p * 32 (= q_s * 256)
// ---------------------------------------------------------------------------
__global__ __launch_bounds__(256) void softmax_q_kernel(
    const float* __restrict__ qkv, f16* __restrict__ qth, f16* __restrict__ qtl)
{
    long idx = (long)blockIdx.x * 256 + threadIdx.x;   // B*H*N total
    int n = (int)(idx & (NN - 1));
    long bh = idx >> 12;
    int h = (int)(bh & (HH - 1));
    int b = (int)(bh >> 3);
    const float* base = qkv + ((long)b * OC3 + (long)h * DD) * NN + n;

    float v[DD];
    float mx = -INFINITY;
    #pragma unroll
    for (int d = 0; d < DD; ++d) {
        v[d] = base[(long)d * NN];
        mx = fmaxf(mx, v[d]);
    }
    float s = 0.f;
    #pragma unroll
    for (int d = 0; d < DD; ++d) {
        v[d] = expf(v[d] - mx);
        s += v[d];
    }
    float r = 32.f / s;     // p * 32 == q_s * 256

    long obase = ((long)b * NN + n) * CD + (long)h * DD;
    #pragma unroll
    for (int d0 = 0; d0 < DD; d0 += 8) {
        half8 hh, ll;
        #pragma unroll
        for (int j = 0; j < 8; ++j) {
            float tval = v[d0 + j] * r;
            f16 hv = (f16)tval;
            hh[j] = hv;
            ll[j] = (f16)(tval - (float)hv);
        }
        *(half8*)(&qth[obase + d0]) = hh;
        *(half8*)(&qtl[obase + d0]) = ll;
    }
}

// ---------------------------------------------------------------------------
// k softmax over tokens (4096 contiguous); emit split-f16 k_s * 4096 into
// the (dead) q region of qkv: kh at bytes [0,4MB), kl at [4,8MB) per batch.
// ---------------------------------------------------------------------------
__global__ __launch_bounds__(256) void softmax_k_kernel(float* __restrict__ qkv)
{
    int row = blockIdx.x;              // b*512 + hd
    int b = row >> 9;
    int hd = row & (CD - 1);
    const float* base = qkv + ((long)b * OC3 + CD + hd) * NN;
    f16* khb = (f16*)(qkv + (long)b * OC3 * NN) + (long)hd * NN;
    f16* klb = khb + (long)CD * NN;
    int t = threadIdx.x;

    float v[16];
    #pragma unroll
    for (int i = 0; i < 16; ++i) v[i] = base[t + i * 256];

    __shared__ float red[256];
    float mx = -INFINITY;
    #pragma unroll
    for (int i = 0; i < 16; ++i) mx = fmaxf(mx, v[i]);
    red[t] = mx; __syncthreads();
    for (int off = 128; off > 0; off >>= 1) {
        if (t < off) red[t] = fmaxf(red[t], red[t + off]);
        __syncthreads();
    }
    mx = red[0]; __syncthreads();

    float s = 0.f;
    #pragma unroll
    for (int i = 0; i < 16; ++i) {
        v[i] = expf(v[i] - mx);
        s += v[i];
    }
    red[t] = s; __syncthreads();
    for (int off = 128; off > 0; off >>= 1) {
        if (t < off) red[t] += red[t + off];
        __syncthreads();
    }
    float inv = 4096.f / red[0];       // k_s scaled by 2^12 for f16 split

    #pragma unroll
    for (int i = 0; i < 16; ++i) {
        float val = v[i] * inv;
        f16 hv = (f16)val;
        khb[t + i * 256] = hv;
        klb[t + i * 256] = (f16)(val - (float)hv);
    }
}

// ---------------------------------------------------------------------------
// context partials via split-f16 MFMA: per (bh, sp) block computes
// acc[64 d][64 e] = sum over 256 n of (k_s*2^12)(v*2^4), 3 products.
// 4 waves: wave w owns cols w*16..w*16+15 and stages array w.
// ---------------------------------------------------------------------------
__global__ __launch_bounds__(256) void ctx_mfma_kernel(
    const float* __restrict__ qkv, float* __restrict__ ctxp)
{
    __shared__ f16 lds[4][64 * 32];          // kh,kl,vh,vl tiles; 4 KB each
    int sp = blockIdx.x;                     // K-split 0..15
    int bh = blockIdx.y;                     // 0..63
    int b = bh >> 3, h = bh & 7;
    int t = threadIdx.x, lane = t & 63, w = t >> 6;

    const char* khg = (const char*)(qkv + (long)b * OC3 * NN) + (long)h * 64 * (NN * 2);
    const char* klg = khg + (long)CD * NN * 2;
    const char* vhg = (const char*)(qkv + ((long)b * OC3 + 2L * CD) * NN) + (long)h * 64 * (NN * 2);
    const char* vlg = vhg + (long)CD * NN * 2;
    const char* gw = (w == 0) ? khg : (w == 1) ? klg : (w == 2) ? vhg : vlg;

    int cl = (lane & 3) ^ ((lane >> 3) & 3);
    char* larr = (char*)&lds[0][0] + w * 4096;
    char* L = (char*)&lds[0][0];
    int cp16 = ((lane >> 4) ^ (((lane & 15) >> 1) & 3)) * 16;
    int lr = lane & 15;

    f32x4 acc[4];
    #pragma unroll
    for (int i = 0; i < 4; ++i) acc[i] = (f32x4){0.f, 0.f, 0.f, 0.f};

    for (int ks = 0; ks < 8; ++ks) {
        long kbyte = ((long)sp * 256 + ks * 32) * 2;
        #pragma unroll
        for (int c = 0; c < 4; ++c)
            gload_lds16(gw + (long)(c * 16 + (lane >> 2)) * (NN * 2) + kbyte + (long)cl * 16,
                        larr + c * 1024 + lane * 16);
        asm volatile("s_waitcnt vmcnt(0)" ::: "memory");
        __syncthreads();

        half8 ah[4], al[4], bhf, blf;
        #pragma unroll
        for (int i = 0; i < 4; ++i) {
            ah[i] = *(const half8*)(L + 0 * 4096 + (i * 16 + lr) * 64 + cp16);
            al[i] = *(const half8*)(L + 1 * 4096 + (i * 16 + lr) * 64 + cp16);
        }
        bhf = *(const half8*)(L + 2 * 4096 + (w * 16 + lr) * 64 + cp16);
        blf = *(const half8*)(L + 3 * 4096 + (w * 16 + lr) * 64 + cp16);
        #pragma unroll
        for (int i = 0; i < 4; ++i) {
            acc[i] = __builtin_amdgcn_mfma_f32_16x16x32_f16(ah[i], bhf, acc[i], 0, 0, 0);
            acc[i] = __builtin_amdgcn_mfma_f32_16x16x32_f16(ah[i], blf, acc[i], 0, 0, 0);
            acc[i] = __builtin_amdgcn_mfma_f32_16x16x32_f16(al[i], bhf, acc[i], 0, 0, 0);
        }
        __syncthreads();
    }

    float* op = ctxp + ((long)bh * NSPLIT + sp) * 4096;
    #pragma unroll
    for (int i = 0; i < 4; ++i)
        #pragma unroll
        for (int r = 0; r < 4; ++r)
            op[(i * 16 + (lane >> 4) * 4 + r) * 64 + w * 16 + lr] = acc[i][r];
}

// ---------------------------------------------------------------------------
// reduce partials in fp64; undo scales: /(2^12 * 2^4) and /N  => * 2^-28
// ---------------------------------------------------------------------------
__global__ __launch_bounds__(256) void context_reduce_kernel(
    const float* __restrict__ ctxp, float* __restrict__ ctx)
{
    int idx = blockIdx.x * 256 + threadIdx.x;
    int bh = idx >> 12;
    int de = idx & 4095;
    double s = 0.0;
    #pragma unroll
    for (int sp = 0; sp < NSPLIT; ++sp)
        s += (double)ctxp[((long)bh * NSPLIT + sp) * 4096 + de];
    ctx[idx] = (float)(s * (1.0 / 268435456.0));
}

// ---------------------------------------------------------------------------
// fold w_out into per-batch M (row-major [c][hd], hd fast -> coalesced)
// ---------------------------------------------------------------------------
__global__ __launch_bounds__(256) void fold_wout_kernel(
    const float* __restrict__ w_out, const float* __restrict__ ctx,
    float* __restrict__ Mf)
{
    long idx = (long)blockIdx.x * 256 + threadIdx.x;   // B*512*512
    int hd = (int)(idx & (CD - 1));
    int c  = (int)((idx >> 9) & (CD - 1));
    int b  = (int)(idx >> 18);
    int h = hd >> 6, d = hd & 63;
    const float* wrow = w_out + (long)c * CD + (long)h * DD;
    const float* crow = ctx + (((long)(b * HH + h) * DD + d) * DD);
    float s = 0.f;
    #pragma unroll
    for (int e = 0; e < DD; e += 4) {
        float4 wv = *reinterpret_cast<const float4*>(&wrow[e]);
        float4 cv = *reinterpret_cast<const float4*>(&crow[e]);
        s += wv.x * cv.x + wv.y * cv.y + wv.z * cv.z + wv.w * cv.w;
    }
    Mf[idx] = s;
}

// ---------------------------------------------------------------------------
// per-batch max|M| -> power-of-2 scale (max*scale in [1024,2048))
// ---------------------------------------------------------------------------
__global__ __launch_bounds__(256) void max_m_kernel(
    const float* __restrict__ Mf, float* __restrict__ scl)
{
    int b = blockIdx.x;
    const float4* p = (const float4*)(Mf + (long)b * CD * CD);
    float mx = 0.f;
    for (int i = threadIdx.x; i < CD * CD / 4; i += 256) {
        float4 v = p[i];
        mx = fmaxf(mx, fmaxf(fmaxf(fabsf(v.x), fabsf(v.y)),
                             fmaxf(fabsf(v.z), fabsf(v.w))));
    }
    __shared__ float red[256];
    red[threadIdx.x] = mx; __syncthreads();
    for (int off = 128; off > 0; off >>= 1) {
        if (threadIdx.x < off) red[threadIdx.x] = fmaxf(red[threadIdx.x], red[threadIdx.x + off]);
        __syncthreads();
    }
    if (threadIdx.x == 0) {
        float m = red[0];
        int e = (m > 1e-30f) ? ilogbf(m) : 0;
        scl[b] = ldexpf(1.f, 10 - e);
        scl[8 + b] = ldexpf(1.f, e - 10);
    }
}

// ---------------------------------------------------------------------------
// split M fp32 -> mh/ml f16 with per-batch scale
// ---------------------------------------------------------------------------
__global__ __launch_bounds__(256) void split_m_kernel(
    const float* __restrict__ Mf, const float* __restrict__ scl,
    f16* __restrict__ mh, f16* __restrict__ ml)
{
    int idx = blockIdx.x * 256 + threadIdx.x;   // BB*CD*CD/4 float4s
    float s = scl[idx >> 16];                   // 65536 float4s per batch
    float4 v = ((const float4*)Mf)[idx];
    float a[4] = {v.x, v.y, v.z, v.w};
    half4v h, l;
    #pragma unroll
    for (int i = 0; i < 4; ++i) {
        float tval = a[i] * s;
        f16 hv = (f16)tval;
        h[i] = hv;
        l[i] = (f16)(tval - (float)hv);
    }
    *(half4v*)(&mh[(long)idx * 4]) = h;
    *(half4v*)(&ml[(long)idx * 4]) = l;
}

// ---------------------------------------------------------------------------
// channel LayerNorm over c=512 (stride NN), fp64 stats, values reg-cached.
// block = 32 cols x 8 c-groups of 64; one global read per element.
// ---------------------------------------------------------------------------
__global__ __launch_bounds__(256) void layernorm_kernel(
    const float* __restrict__ qkv, const float* __restrict__ g,
    float* __restrict__ out)
{
    int t = threadIdx.x;
    int tn = t & 31, cy = t >> 5;              // col-in-block, c-group
    long col = (long)blockIdx.x * 32 + tn;     // 0..32767
    int n = (int)(col & (NN - 1));
    int b = (int)(col >> 12);
    const float* base = qkv + (long)b * OC3 * NN + (long)CD * NN + n;

    float v[64];
    double s = 0.0, ss = 0.0;
    #pragma unroll
    for (int i = 0; i < 64; ++i) {
        v[i] = base[(long)(cy * 64 + i) * NN];
        s += (double)v[i];
        ss += (double)v[i] * (double)v[i];
    }

    __shared__ double rs[8][32], rss[8][32];
    rs[cy][tn] = s; rss[cy][tn] = ss;
    __syncthreads();
    __shared__ float mb[32], ib[32];
    if (cy == 0) {
        double S = 0.0, SS = 0.0;
        #pragma unroll
        for (int j = 0; j < 8; ++j) { S += rs[j][tn]; SS += rss[j][tn]; }
        double mean = S * (1.0 / CD);
        double var = SS * (1.0 / CD) - mean * mean;
        mb[tn] = (float)mean;
        ib[tn] = (float)(1.0 / sqrt(var + 1e-5));
    }
    __syncthreads();
    float m = mb[tn], iv = ib[tn];

    float* oc = out + (long)b * CD * NN + n;
    #pragma unroll
    for (int i = 0; i < 64; ++i)
        oc[(long)(cy * 64 + i) * NN] = (v[i] - m) * iv * g[cy * 64 + i];
}

// ---------------------------------------------------------------------------
extern "C" void kernel_launch(void* const* d_in, const int* in_sizes, int n_in,
                              void* d_out, int out_size, void* d_ws, size_t ws_size,
                              hipStream_t stream)
{
    const float* x     = (const float*)d_in[0];
    const float* w_qkv = (const float*)d_in[1];
    const float* w_out = (const float*)d_in[2];
    const float* b_out = (const float*)d_in[3];
    const float* g     = (const float*)d_in[4];
    float* out = (float*)d_out;

    float* ws   = (float*)d_ws;
    float* qkv  = ws;                                      // 50,331,648 f
    float* ctxp = qkv + (long)BB * OC3 * NN;               //  4,194,304 f (reused for Mf)
    float* ctx  = ctxp + (long)BB * HH * NSPLIT * DD * DD; //    262,144 f
    f16*   mh   = (f16*)(ctx + (long)BB * HH * DD * DD);   //  2,097,152 h
    f16*   ml   = mh + (long)BB * CD * CD;                 //  2,097,152 h
    f16*   wh   = (f16*)(ml + (long)BB * CD * CD);         //    786,432 h
    f16*   wl   = wh + (long)OC3 * CD;                     //    786,432 h
    float* scl  = (float*)(wl + (long)OC3 * CD);           //         16 f
    float* Mf   = ctxp;                                    // ctxp dead by then

    // d_out as scratch: xth/xtl (phase 1), then qth/qtl (phase 2); LN
    // overwrites at the end.
    f16* xth = (f16*)d_out;
    f16* xtl = xth + (long)BB * NN * CD;
    f16* qth = xth;
    f16* qtl = xtl;

    // 0) operand splits
    split_w_kernel<<<(OC3 * CD / 4) / 256, 256, 0, stream>>>(w_qkv, wh, wl);
    split_x_kernel<<<dim3(NN / 32, CD / 32, BB), dim3(32, 8), 0, stream>>>(x, xth, xtl);

    // 1) qkv = w_qkv @ x via split-f16 MFMA. q,k thirds -> fp32; v third ->
    //    split-f16 (x16) straight into qkv's v region (no fp32 v write).
    mfma_gemm_kernel<<<dim3(NN / 128, OC3 / 128, BB), 256, 0, stream>>>(
        wh, wl, 0L, xth, xtl, (long)NN * CD,
        qkv, (long)OC3 * NN, NN, nullptr, nullptr, 1.0f / 1024.0f, (f16*)qkv);

    // 2) softmaxes: q -> split-f16 transposed in d_out; k -> split-f16 k_s
    //    (x4096) into the dead q region
    softmax_q_kernel<<<(BB * HH * NN) / 256, 256, 0, stream>>>(qkv, qth, qtl);
    softmax_k_kernel<<<BB * CD, 256, 0, stream>>>(qkv);

    // 3) context via MFMA partials + fp64 reduce (undoes 2^16 scale and /N)
    ctx_mfma_kernel<<<dim3(NSPLIT, BB * HH), 256, 0, stream>>>(qkv, ctxp);
    context_reduce_kernel<<<(BB * HH * DD * DD) / 256, 256, 0, stream>>>(ctxp, ctx);

    // 4) M = fold(w_out, ctx) fp32 -> dynamic per-batch pow2 scale -> f16 split
    fold_wout_kernel<<<(BB * CD * CD) / 256, 256, 0, stream>>>(w_out, ctx, Mf);
    max_m_kernel<<<BB, 256, 0, stream>>>(Mf, scl);
    split_m_kernel<<<(BB * CD * CD / 4) / 256, 256, 0, stream>>>(Mf, scl, mh, ml);

    // 5) y = M_b @ q_s + b_out via split-f16 MFMA -> dead k region of qkv
    mfma_gemm_kernel<<<dim3(NN / 128, CD / 128, BB), 256, 0, stream>>>(
        mh, ml, (long)CD * CD, qth, qtl, (long)NN * CD,
        qkv + (long)CD * NN, (long)OC3 * NN, NN, b_out, scl + 8, 1.0f / 256.0f,
        nullptr);

    // 6) channel LayerNorm -> d_out (overwrites q scratch)
    layernorm_kernel<<<(BB * NN) / 32, 256, 0, stream>>>(qkv, g, out);
}

// Round 6
// 521.406 us; speedup vs baseline: 2.4730x; 1.0107x over previous
//
#include <hip/hip_runtime.h>
#include <math.h>

// Problem constants
#define BB 8
#define NN 4096      // 64*64 tokens
#define CD 512       // channels
#define HH 8
#define DD 64
#define OC3 1536     // 3*hidden
#define NSPLIT 16

typedef _Float16 f16;
typedef _Float16 half8 __attribute__((ext_vector_type(8)));
typedef _Float16 half4v __attribute__((ext_vector_type(4)));
typedef float f32x4 __attribute__((ext_vector_type(4)));

__device__ __forceinline__ void gload_lds16(const void* g, void* l) {
    __builtin_amdgcn_global_load_lds(
        (const __attribute__((address_space(1))) unsigned int*)g,
        (__attribute__((address_space(3))) unsigned int*)l, 16, 0, 0);
}

// ---------------------------------------------------------------------------
// split w_qkv [1536][512] f32 -> wh, wl [1536][512] f16, scaled by 64
// ---------------------------------------------------------------------------
__global__ __launch_bounds__(256) void split_w_kernel(
    const float* __restrict__ w, f16* __restrict__ wh, f16* __restrict__ wl)
{
    int idx = blockIdx.x * 256 + threadIdx.x;      // OC3*CD/4 = 196608 total
    float4 v = ((const float4*)w)[idx];
    float a[4] = {v.x, v.y, v.z, v.w};
    half4v h, l;
    #pragma unroll
    for (int i = 0; i < 4; ++i) {
        float s = a[i] * 64.f;
        f16 hh = (f16)s;
        h[i] = hh;
        l[i] = (f16)(s - (float)hh);
    }
    *(half4v*)(&wh[(long)idx * 4]) = h;
    *(half4v*)(&wl[(long)idx * 4]) = l;
}

// ---------------------------------------------------------------------------
// split + transpose x [b][512 c][4096 n] f32 -> xth, xtl [b][4096 n][512 c]
// f16, scaled by 16.  64x64 tile, half8 (16B) coalesced writes.
// ---------------------------------------------------------------------------
__global__ __launch_bounds__(256) void split_x_kernel(
    const float* __restrict__ x, f16* __restrict__ xth, f16* __restrict__ xtl)
{
    __shared__ float tile[64][65];
    int b = blockIdx.z;
    int n0 = blockIdx.x * 64, c0 = blockIdx.y * 64;
    const float* xb = x + ((long)b * CD + c0) * NN + n0;
    int t = threadIdx.x;
    int tr = t >> 6, tc = t & 63;
    #pragma unroll
    for (int i = 0; i < 16; ++i)
        tile[tr + i * 4][tc] = xb[(long)(tr + i * 4) * NN + tc];
    __syncthreads();

    int nl = t >> 3, ck = (t & 7) * 8;
    long obase = ((long)b * NN + n0) * CD + c0;
    #pragma unroll
    for (int p = 0; p < 2; ++p) {
        int n = nl + p * 32;
        half8 h, l;
        #pragma unroll
        for (int j = 0; j < 8; ++j) {
            float s = tile[ck + j][n] * 16.f;
            f16 hv = (f16)s;
            h[j] = hv;
            l[j] = (f16)(s - (float)hv);
        }
        *(half8*)(&xth[obase + (long)n * CD + ck]) = h;
        *(half8*)(&xtl[obase + (long)n * CD + ck]) = l;
    }
}

// ---------------------------------------------------------------------------
// Shared split-f16 MFMA GEMM, K=512 fixed. 3 products hh+hl+lh, fp32 accum.
// Block 256 (4 waves 2x2), tile 128x128, wave 64x64, KT=32.
// T3 minimal 2-phase: double-buffered LDS (2 x 32KB), stage(next) issued
// before compute(cur), single vmcnt(0)+barrier per K-step (stage latency
// hides under the 48 MFMAs).
// If vout != nullptr: blocks with m0 >= 1024 (the v third of qkv) write
// split-f16 v (scale x16) into the v region instead of fp32.
// ---------------------------------------------------------------------------
#define STAGE(Lb, k0s)  do {                                                   \
    long kb_ = (long)(k0s) * 2;                                                \
    _Pragma("unroll")                                                          \
    for (int c_ = 0; c_ < 2; ++c_) {                                           \
        long rowoff_ = (long)(rb0 + c_ * 16) * 1024;                           \
        long ldsoff_ = (long)(rb0 + c_ * 16) * 64;                             \
        gload_lds16(gA_h + rowoff_ + kb_ + g_lane, (Lb) + 0 * 8192 + ldsoff_); \
        gload_lds16(gA_l + rowoff_ + kb_ + g_lane, (Lb) + 1 * 8192 + ldsoff_); \
        gload_lds16(gB_h + rowoff_ + kb_ + g_lane, (Lb) + 2 * 8192 + ldsoff_); \
        gload_lds16(gB_l + rowoff_ + kb_ + g_lane, (Lb) + 3 * 8192 + ldsoff_); \
    } } while (0)

__global__ __launch_bounds__(256) void mfma_gemm_kernel(
    const f16* __restrict__ Ah, const f16* __restrict__ Al, long sA,
    const f16* __restrict__ Bh, const f16* __restrict__ Bl, long sB,
    float* __restrict__ Cp, long sC, int ldC,
    const float* __restrict__ bias, const float* __restrict__ inv_sc,
    float base_sc, f16* __restrict__ vout)
{
    __shared__ f16 lds[2][4][128 * 32];  // [dbuf][Ah,Al,Bh,Bl]; 64 KB total
    int bz = blockIdx.z;
    int n0 = blockIdx.x * 128, m0 = blockIdx.y * 128;
    int t = threadIdx.x;
    int lane = t & 63, wid = t >> 6;
    int wy = wid >> 1, wx = wid & 1;

    // staging: physical chunk = lane&3, logical chunk = (lane&3)^((row>>1)&3)
    int cl = (lane & 3) ^ ((lane >> 3) & 3);
    long g_lane = (long)(lane >> 2) * 1024 + (long)cl * 16;   // row = 512 f16 = 1024 B

    const char* gA_h = (const char*)(Ah + bz * sA) + (long)m0 * 1024;
    const char* gA_l = (const char*)(Al + bz * sA) + (long)m0 * 1024;
    const char* gB_h = (const char*)(Bh + bz * sB) + (long)n0 * 1024;
    const char* gB_l = (const char*)(Bl + bz * sB) + (long)n0 * 1024;

    char* L0 = (char*)&lds[0][0][0];
    int rb0 = wid * 32;                  // this wave stages rows rb0..rb0+31

    // frag read: want logical chunk (lane>>4); read physical
    int cp = (lane >> 4) ^ (((lane & 15) >> 1) & 3);
    long offA = (long)(wy * 64 + (lane & 15)) * 64 + (long)cp * 16;
    long offB = (long)(wx * 64 + (lane & 15)) * 64 + (long)cp * 16;

    f32x4 acc[4][4];
    #pragma unroll
    for (int i = 0; i < 4; ++i)
        #pragma unroll
        for (int j = 0; j < 4; ++j)
            acc[i][j] = (f32x4){0.f, 0.f, 0.f, 0.f};

    STAGE(L0, 0);
    asm volatile("s_waitcnt vmcnt(0)" ::: "memory");
    __syncthreads();

    for (int s = 0; s < 16; ++s) {
        char* Lc = L0 + ((s & 1) << 15);
        if (s < 15) {
            char* Ln = L0 + (((s + 1) & 1) << 15);
            STAGE(Ln, (s + 1) * 32);
        }

        half8 ah[4], al[4], bh[4], bl[4];
        #pragma unroll
        for (int i = 0; i < 4; ++i) {
            ah[i] = *(const half8*)(Lc + 0 * 8192 + offA + i * 1024);
            al[i] = *(const half8*)(Lc + 1 * 8192 + offA + i * 1024);
            bh[i] = *(const half8*)(Lc + 2 * 8192 + offB + i * 1024);
            bl[i] = *(const half8*)(Lc + 3 * 8192 + offB + i * 1024);
        }
        #pragma unroll
        for (int i = 0; i < 4; ++i)
            #pragma unroll
            for (int j = 0; j < 4; ++j) {
                acc[i][j] = __builtin_amdgcn_mfma_f32_16x16x32_f16(ah[i], bh[j], acc[i][j], 0, 0, 0);
                acc[i][j] = __builtin_amdgcn_mfma_f32_16x16x32_f16(ah[i], bl[j], acc[i][j], 0, 0, 0);
                acc[i][j] = __builtin_amdgcn_mfma_f32_16x16x32_f16(al[i], bh[j], acc[i][j], 0, 0, 0);
            }

        asm volatile("s_waitcnt vmcnt(0)" ::: "memory");
        __syncthreads();
    }

    // C/D layout: col = lane&15, row = (lane>>4)*4 + reg
    int colb = n0 + wx * 64 + (lane & 15);
    int rowb = m0 + wy * 64 + ((lane >> 4) << 2);

    if (vout && m0 >= 1024) {
        // v third: emit split-f16 (value = v_true * 16) into qkv's v region
        long vbase2 = 2L * ((long)bz * OC3 * NN + 2L * CD * NN);
        f16* vhp = vout + vbase2;
        f16* vlp = vhp + (long)CD * NN;
        float vsc = base_sc * 16.f;
        #pragma unroll
        for (int i = 0; i < 4; ++i)
            #pragma unroll
            for (int j = 0; j < 4; ++j)
                #pragma unroll
                for (int r = 0; r < 4; ++r) {
                    long row = rowb + i * 16 + r - 1024;
                    float val = acc[i][j][r] * vsc;
                    f16 hv = (f16)val;
                    vhp[row * NN + colb + j * 16] = hv;
                    vlp[row * NN + colb + j * 16] = (f16)(val - (float)hv);
                }
        return;
    }

    float* outp = Cp + bz * sC;
    float mult = base_sc * (inv_sc ? inv_sc[bz] : 1.f);
    #pragma unroll
    for (int i = 0; i < 4; ++i)
        #pragma unroll
        for (int j = 0; j < 4; ++j)
            #pragma unroll
            for (int r = 0; r < 4; ++r) {
                int row = rowb + i * 16 + r;
                float bb = bias ? bias[row] : 0.f;
                outp[(long)row * ldC + colb + j * 16] = acc[i][j][r] * mult + bb;
            }
}

// ---------------------------------------------------------------------------
// q softmax over head_dim (strided read), emit split-f16 TRANSPOSED:
// qth/qtl [b][n][512], values = p * 32 (= q_s * 256)
// ---------------------------------------------------------------------------
__global__ __launch_bounds__(256) void softmax_q_kernel(
    const float* __restrict__ qkv, f16* __restrict__ qth, f16* __restrict__ qtl)
{
    long idx = (long)blockIdx.x * 256 + threadIdx.x;   // B*H*N total
    int n = (int)(idx & (NN - 1));
    long bh = idx >> 12;
    int h = (int)(bh & (HH - 1));
    int b = (int)(bh >> 3);
    const float* base = qkv + ((long)b * OC3 + (long)h * DD) * NN + n;

    float v[DD];
    float mx = -INFINITY;
    #pragma unroll
    for (int d = 0; d < DD; ++d) {
        v[d] = base[(long)d * NN];
        mx = fmaxf(mx, v[d]);
    }
    float s = 0.f;
    #pragma unroll
    for (int d = 0; d < DD; ++d) {
        v[d] = expf(v[d] - mx);
        s += v[d];
    }
    float r = 32.f / s;     // p * 32 == q_s * 256

    long obase = ((long)b * NN + n) * CD + (long)h * DD;
    #pragma unroll
    for (int d0 = 0; d0 < DD; d0 += 8) {
        half8 hh, ll;
        #pragma unroll
        for (int j = 0; j < 8; ++j) {
            float tval = v[d0 + j] * r;
            f16 hv = (f16)tval;
            hh[j] = hv;
            ll[j] = (f16)(tval - (float)hv);
        }
        *(half8*)(&qth[obase + d0]) = hh;
        *(half8*)(&qtl[obase + d0]) = ll;
    }
}

// ---------------------------------------------------------------------------
// k softmax over tokens (4096 contiguous); emit split-f16 k_s * 4096 into
// the (dead) q region of qkv: kh at bytes [0,4MB), kl at [4,8MB) per batch.
// ---------------------------------------------------------------------------
__global__ __launch_bounds__(256) void softmax_k_kernel(float* __restrict__ qkv)
{
    int row = blockIdx.x;              // b*512 + hd
    int b = row >> 9;
    int hd = row & (CD - 1);
    const float* base = qkv + ((long)b * OC3 + CD + hd) * NN;
    f16* khb = (f16*)(qkv + (long)b * OC3 * NN) + (long)hd * NN;
    f16* klb = khb + (long)CD * NN;
    int t = threadIdx.x;

    float v[16];
    #pragma unroll
    for (int i = 0; i < 16; ++i) v[i] = base[t + i * 256];

    __shared__ float red[256];
    float mx = -INFINITY;
    #pragma unroll
    for (int i = 0; i < 16; ++i) mx = fmaxf(mx, v[i]);
    red[t] = mx; __syncthreads();
    for (int off = 128; off > 0; off >>= 1) {
        if (t < off) red[t] = fmaxf(red[t], red[t + off]);
        __syncthreads();
    }
    mx = red[0]; __syncthreads();

    float s = 0.f;
    #pragma unroll
    for (int i = 0; i < 16; ++i) {
        v[i] = expf(v[i] - mx);
        s += v[i];
    }
    red[t] = s; __syncthreads();
    for (int off = 128; off > 0; off >>= 1) {
        if (t < off) red[t] += red[t + off];
        __syncthreads();
    }
    float inv = 4096.f / red[0];       // k_s scaled by 2^12 for f16 split

    #pragma unroll
    for (int i = 0; i < 16; ++i) {
        float val = v[i] * inv;
        f16 hv = (f16)val;
        khb[t + i * 256] = hv;
        klb[t + i * 256] = (f16)(val - (float)hv);
    }
}

// ---------------------------------------------------------------------------
// context partials via split-f16 MFMA: per (bh, sp) block computes
// acc[64 d][64 e] = sum over 256 n of (k_s*2^12)(v*2^4), 3 products.
// 4 waves: wave w owns cols w*16..w*16+15 and stages array w.
// ---------------------------------------------------------------------------
__global__ __launch_bounds__(256) void ctx_mfma_kernel(
    const float* __restrict__ qkv, float* __restrict__ ctxp)
{
    __shared__ f16 lds[4][64 * 32];          // kh,kl,vh,vl tiles; 4 KB each
    int sp = blockIdx.x;                     // K-split 0..15
    int bh = blockIdx.y;                     // 0..63
    int b = bh >> 3, h = bh & 7;
    int t = threadIdx.x, lane = t & 63, w = t >> 6;

    const char* khg = (const char*)(qkv + (long)b * OC3 * NN) + (long)h * 64 * (NN * 2);
    const char* klg = khg + (long)CD * NN * 2;
    const char* vhg = (const char*)(qkv + ((long)b * OC3 + 2L * CD) * NN) + (long)h * 64 * (NN * 2);
    const char* vlg = vhg + (long)CD * NN * 2;
    const char* gw = (w == 0) ? khg : (w == 1) ? klg : (w == 2) ? vhg : vlg;

    int cl = (lane & 3) ^ ((lane >> 3) & 3);
    char* larr = (char*)&lds[0][0] + w * 4096;
    char* L = (char*)&lds[0][0];
    int cp16 = ((lane >> 4) ^ (((lane & 15) >> 1) & 3)) * 16;
    int lr = lane & 15;

    f32x4 acc[4];
    #pragma unroll
    for (int i = 0; i < 4; ++i) acc[i] = (f32x4){0.f, 0.f, 0.f, 0.f};

    for (int ks = 0; ks < 8; ++ks) {
        long kbyte = ((long)sp * 256 + ks * 32) * 2;
        #pragma unroll
        for (int c = 0; c < 4; ++c)
            gload_lds16(gw + (long)(c * 16 + (lane >> 2)) * (NN * 2) + kbyte + (long)cl * 16,
                        larr + c * 1024 + lane * 16);
        asm volatile("s_waitcnt vmcnt(0)" ::: "memory");
        __syncthreads();

        half8 ah[4], al[4], bhf, blf;
        #pragma unroll
        for (int i = 0; i < 4; ++i) {
            ah[i] = *(const half8*)(L + 0 * 4096 + (i * 16 + lr) * 64 + cp16);
            al[i] = *(const half8*)(L + 1 * 4096 + (i * 16 + lr) * 64 + cp16);
        }
        bhf = *(const half8*)(L + 2 * 4096 + (w * 16 + lr) * 64 + cp16);
        blf = *(const half8*)(L + 3 * 4096 + (w * 16 + lr) * 64 + cp16);
        #pragma unroll
        for (int i = 0; i < 4; ++i) {
            acc[i] = __builtin_amdgcn_mfma_f32_16x16x32_f16(ah[i], bhf, acc[i], 0, 0, 0);
            acc[i] = __builtin_amdgcn_mfma_f32_16x16x32_f16(ah[i], blf, acc[i], 0, 0, 0);
            acc[i] = __builtin_amdgcn_mfma_f32_16x16x32_f16(al[i], bhf, acc[i], 0, 0, 0);
        }
        __syncthreads();
    }

    float* op = ctxp + ((long)bh * NSPLIT + sp) * 4096;
    #pragma unroll
    for (int i = 0; i < 4; ++i)
        #pragma unroll
        for (int r = 0; r < 4; ++r)
            op[(i * 16 + (lane >> 4) * 4 + r) * 64 + w * 16 + lr] = acc[i][r];
}

// ---------------------------------------------------------------------------
// reduce partials in fp64; undo scales: /(2^12 * 2^4) and /N  => * 2^-28
// ---------------------------------------------------------------------------
__global__ __launch_bounds__(256) void context_reduce_kernel(
    const float* __restrict__ ctxp, float* __restrict__ ctx)
{
    int idx = blockIdx.x * 256 + threadIdx.x;
    int bh = idx >> 12;
    int de = idx & 4095;
    double s = 0.0;
    #pragma unroll
    for (int sp = 0; sp < NSPLIT; ++sp)
        s += (double)ctxp[((long)bh * NSPLIT + sp) * 4096 + de];
    ctx[idx] = (float)(s * (1.0 / 268435456.0));
}

// ---------------------------------------------------------------------------
// fold w_out into per-batch M (row-major [c][hd], hd fast -> coalesced)
// ---------------------------------------------------------------------------
__global__ __launch_bounds__(256) void fold_wout_kernel(
    const float* __restrict__ w_out, const float* __restrict__ ctx,
    float* __restrict__ Mf)
{
    long idx = (long)blockIdx.x * 256 + threadIdx.x;   // B*512*512
    int hd = (int)(idx & (CD - 1));
    int c  = (int)((idx >> 9) & (CD - 1));
    int b  = (int)(idx >> 18);
    int h = hd >> 6, d = hd & 63;
    const float* wrow = w_out + (long)c * CD + (long)h * DD;
    const float* crow = ctx + (((long)(b * HH + h) * DD + d) * DD);
    float s = 0.f;
    #pragma unroll
    for (int e = 0; e < DD; e += 4) {
        float4 wv = *reinterpret_cast<const float4*>(&wrow[e]);
        float4 cv = *reinterpret_cast<const float4*>(&crow[e]);
        s += wv.x * cv.x + wv.y * cv.y + wv.z * cv.z + wv.w * cv.w;
    }
    Mf[idx] = s;
}

// ---------------------------------------------------------------------------
// per-batch max|M| -> power-of-2 scale (max*scale in [1024,2048))
// ---------------------------------------------------------------------------
__global__ __launch_bounds__(256) void max_m_kernel(
    const float* __restrict__ Mf, float* __restrict__ scl)
{
    int b = blockIdx.x;
    const float4* p = (const float4*)(Mf + (long)b * CD * CD);
    float mx = 0.f;
    for (int i = threadIdx.x; i < CD * CD / 4; i += 256) {
        float4 v = p[i];
        mx = fmaxf(mx, fmaxf(fmaxf(fabsf(v.x), fabsf(v.y)),
                             fmaxf(fabsf(v.z), fabsf(v.w))));
    }
    __shared__ float red[256];
    red[threadIdx.x] = mx; __syncthreads();
    for (int off = 128; off > 0; off >>= 1) {
        if (threadIdx.x < off) red[threadIdx.x] = fmaxf(red[threadIdx.x], red[threadIdx.x + off]);
        __syncthreads();
    }
    if (threadIdx.x == 0) {
        float m = red[0];
        int e = (m > 1e-30f) ? ilogbf(m) : 0;
        scl[b] = ldexpf(1.f, 10 - e);
        scl[8 + b] = ldexpf(1.f, e - 10);
    }
}

// ---------------------------------------------------------------------------
// split M fp32 -> mh/ml f16 with per-batch scale
// ---------------------------------------------------------------------------
__global__ __launch_bounds__(256) void split_m_kernel(
    const float* __restrict__ Mf, const float* __restrict__ scl,
    f16* __restrict__ mh, f16* __restrict__ ml)
{
    int idx = blockIdx.x * 256 + threadIdx.x;   // BB*CD*CD/4 float4s
    float s = scl[idx >> 16];                   // 65536 float4s per batch
    float4 v = ((const float4*)Mf)[idx];
    float a[4] = {v.x, v.y, v.z, v.w};
    half4v h, l;
    #pragma unroll
    for (int i = 0; i < 4; ++i) {
        float tval = a[i] * s;
        f16 hv = (f16)tval;
        h[i] = hv;
        l[i] = (f16)(tval - (float)hv);
    }
    *(half4v*)(&mh[(long)idx * 4]) = h;
    *(half4v*)(&ml[(long)idx * 4]) = l;
}

// ---------------------------------------------------------------------------
// channel LayerNorm over c=512 (stride NN), fp64 stats, values reg-cached.
// block = 32 cols x 8 c-groups of 64; one global read per element.
// ---------------------------------------------------------------------------
__global__ __launch_bounds__(256) void layernorm_kernel(
    const float* __restrict__ qkv, const float* __restrict__ g,
    float* __restrict__ out)
{
    int t = threadIdx.x;
    int tn = t & 31, cy = t >> 5;              // col-in-block, c-group
    long col = (long)blockIdx.x * 32 + tn;     // 0..32767
    int n = (int)(col & (NN - 1));
    int b = (int)(col >> 12);
    const float* base = qkv + (long)b * OC3 * NN + (long)CD * NN + n;

    float v[64];
    double s = 0.0, ss = 0.0;
    #pragma unroll
    for (int i = 0; i < 64; ++i) {
        v[i] = base[(long)(cy * 64 + i) * NN];
        s += (double)v[i];
        ss += (double)v[i] * (double)v[i];
    }

    __shared__ double rs[8][32], rss[8][32];
    rs[cy][tn] = s; rss[cy][tn] = ss;
    __syncthreads();
    __shared__ float mb[32], ib[32];
    if (cy == 0) {
        double S = 0.0, SS = 0.0;
        #pragma unroll
        for (int j = 0; j < 8; ++j) { S += rs[j][tn]; SS += rss[j][tn]; }
        double mean = S * (1.0 / CD);
        double var = SS * (1.0 / CD) - mean * mean;
        mb[tn] = (float)mean;
        ib[tn] = (float)(1.0 / sqrt(var + 1e-5));
    }
    __syncthreads();
    float m = mb[tn], iv = ib[tn];

    float* oc = out + (long)b * CD * NN + n;
    #pragma unroll
    for (int i = 0; i < 64; ++i)
        oc[(long)(cy * 64 + i) * NN] = (v[i] - m) * iv * g[cy * 64 + i];
}

// ---------------------------------------------------------------------------
extern "C" void kernel_launch(void* const* d_in, const int* in_sizes, int n_in,
                              void* d_out, int out_size, void* d_ws, size_t ws_size,
                              hipStream_t stream)
{
    const float* x     = (const float*)d_in[0];
    const float* w_qkv = (const float*)d_in[1];
    const float* w_out = (const float*)d_in[2];
    const float* b_out = (const float*)d_in[3];
    const float* g     = (const float*)d_in[4];
    float* out = (float*)d_out;

    float* ws   = (float*)d_ws;
    float* qkv  = ws;                                      // 50,331,648 f
    float* ctxp = qkv + (long)BB * OC3 * NN;               //  4,194,304 f (reused for Mf)
    float* ctx  = ctxp + (long)BB * HH * NSPLIT * DD * DD; //    262,144 f
    f16*   mh   = (f16*)(ctx + (long)BB * HH * DD * DD);   //  2,097,152 h
    f16*   ml   = mh + (long)BB * CD * CD;                 //  2,097,152 h
    f16*   wh   = (f16*)(ml + (long)BB * CD * CD);         //    786,432 h
    f16*   wl   = wh + (long)OC3 * CD;                     //    786,432 h
    float* scl  = (float*)(wl + (long)OC3 * CD);           //         16 f
    float* Mf   = ctxp;                                    // ctxp dead by then

    // d_out as scratch: xth/xtl (phase 1), then qth/qtl (phase 2); LN
    // overwrites at the end.
    f16* xth = (f16*)d_out;
    f16* xtl = xth + (long)BB * NN * CD;
    f16* qth = xth;
    f16* qtl = xtl;

    // 0) operand splits
    split_w_kernel<<<(OC3 * CD / 4) / 256, 256, 0, stream>>>(w_qkv, wh, wl);
    split_x_kernel<<<dim3(NN / 64, CD / 64, BB), 256, 0, stream>>>(x, xth, xtl);

    // 1) qkv = w_qkv @ x via split-f16 MFMA. q,k thirds -> fp32; v third ->
    //    split-f16 (x16) straight into qkv's v region (no fp32 v write).
    mfma_gemm_kernel<<<dim3(NN / 128, OC3 / 128, BB), 256, 0, stream>>>(
        wh, wl, 0L, xth, xtl, (long)NN * CD,
        qkv, (long)OC3 * NN, NN, nullptr, nullptr, 1.0f / 1024.0f, (f16*)qkv);

    // 2) softmaxes: q -> split-f16 transposed in d_out; k -> split-f16 k_s
    //    (x4096) into the dead q region
    softmax_q_kernel<<<(BB * HH * NN) / 256, 256, 0, stream>>>(qkv, qth, qtl);
    softmax_k_kernel<<<BB * CD, 256, 0, stream>>>(qkv);

    // 3) context via MFMA partials + fp64 reduce (undoes 2^16 scale and /N)
    ctx_mfma_kernel<<<dim3(NSPLIT, BB * HH), 256, 0, stream>>>(qkv, ctxp);
    context_reduce_kernel<<<(BB * HH * DD * DD) / 256, 256, 0, stream>>>(ctxp, ctx);

    // 4) M = fold(w_out, ctx) fp32 -> dynamic per-batch pow2 scale -> f16 split
    fold_wout_kernel<<<(BB * CD * CD) / 256, 256, 0, stream>>>(w_out, ctx, Mf);
    max_m_kernel<<<BB, 256, 0, stream>>>(Mf, scl);
    split_m_kernel<<<(BB * CD * CD / 4) / 256, 256, 0, stream>>>(Mf, scl, mh, ml);

    // 5) y = M_b @ q_s + b_out via split-f16 MFMA -> dead k region of qkv
    mfma_gemm_kernel<<<dim3(NN / 128, CD / 128, BB), 256, 0, stream>>>(
        mh, ml, (long)CD * CD, qth, qtl, (long)NN * CD,
        qkv + (long)CD * NN, (long)OC3 * NN, NN, b_out, scl + 8, 1.0f / 256.0f,
        nullptr);

    // 6) channel LayerNorm -> d_out (overwrites q scratch)
    layernorm_kernel<<<(BB * NN) / 32, 256, 0, stream>>>(qkv, g, out);
}

// Round 7
// 415.166 us; speedup vs baseline: 3.1059x; 1.2559x over previous
//
#include <hip/hip_runtime.h>
#include <math.h>

// Problem constants
#define BB 8
#define NN 4096      // 64*64 tokens
#define CD 512       // channels
#define HH 8
#define DD 64
#define OC3 1536     // 3*hidden
#define NSPLIT 16

typedef _Float16 f16;
typedef _Float16 half8 __attribute__((ext_vector_type(8)));
typedef _Float16 half4v __attribute__((ext_vector_type(4)));
typedef float f32x4 __attribute__((ext_vector_type(4)));

__device__ __forceinline__ void gload_lds16(const void* g, void* l) {
    __builtin_amdgcn_global_load_lds(
        (const __attribute__((address_space(1))) unsigned int*)g,
        (__attribute__((address_space(3))) unsigned int*)l, 16, 0, 0);
}

// ---------------------------------------------------------------------------
// split w_qkv [1536][512] f32 -> wh, wl [1536][512] f16, scaled by 64
// ---------------------------------------------------------------------------
__global__ __launch_bounds__(256) void split_w_kernel(
    const float* __restrict__ w, f16* __restrict__ wh, f16* __restrict__ wl)
{
    int idx = blockIdx.x * 256 + threadIdx.x;      // OC3*CD/4 = 196608 total
    float4 v = ((const float4*)w)[idx];
    float a[4] = {v.x, v.y, v.z, v.w};
    half4v h, l;
    #pragma unroll
    for (int i = 0; i < 4; ++i) {
        float s = a[i] * 64.f;
        f16 hh = (f16)s;
        h[i] = hh;
        l[i] = (f16)(s - (float)hh);
    }
    *(half4v*)(&wh[(long)idx * 4]) = h;
    *(half4v*)(&wl[(long)idx * 4]) = l;
}

// ---------------------------------------------------------------------------
// split + transpose x [b][512 c][4096 n] f32 -> xth, xtl [b][4096 n][512 c]
// f16, scaled by 16.  64x64 tile, half8 (16B) coalesced writes.
// ---------------------------------------------------------------------------
__global__ __launch_bounds__(256) void split_x_kernel(
    const float* __restrict__ x, f16* __restrict__ xth, f16* __restrict__ xtl)
{
    __shared__ float tile[64][65];
    int b = blockIdx.z;
    int n0 = blockIdx.x * 64, c0 = blockIdx.y * 64;
    const float* xb = x + ((long)b * CD + c0) * NN + n0;
    int t = threadIdx.x;
    int tr = t >> 6, tc = t & 63;
    #pragma unroll
    for (int i = 0; i < 16; ++i)
        tile[tr + i * 4][tc] = xb[(long)(tr + i * 4) * NN + tc];
    __syncthreads();

    int nl = t >> 3, ck = (t & 7) * 8;
    long obase = ((long)b * NN + n0) * CD + c0;
    #pragma unroll
    for (int p = 0; p < 2; ++p) {
        int n = nl + p * 32;
        half8 h, l;
        #pragma unroll
        for (int j = 0; j < 8; ++j) {
            float s = tile[ck + j][n] * 16.f;
            f16 hv = (f16)s;
            h[j] = hv;
            l[j] = (f16)(s - (float)hv);
        }
        *(half8*)(&xth[obase + (long)n * CD + ck]) = h;
        *(half8*)(&xtl[obase + (long)n * CD + ck]) = l;
    }
}

// ---------------------------------------------------------------------------
// Shared split-f16 MFMA GEMM, K=512 fixed. 3 products hh+hl+lh, fp32 accum.
// Block 256 (4 waves 2x2), tile 128x128, wave 64x64, KT=32, 2-phase dbuf.
// fuseqv != 0 (qkv pass only):
//   m0 <  512 : q third -> fused softmax-over-d (wave tile = one head) and
//               split-f16 write (p*32) into the q region of qkv [n][512] layout
//   m0 >= 1024: v third -> split-f16 (x16) into qkv's v region
//   else      : k third -> fp32
// ---------------------------------------------------------------------------
#define STAGE(Lb, k0s)  do {                                                   \
    long kb_ = (long)(k0s) * 2;                                                \
    _Pragma("unroll")                                                          \
    for (int c_ = 0; c_ < 2; ++c_) {                                           \
        long rowoff_ = (long)(rb0 + c_ * 16) * 1024;                           \
        long ldsoff_ = (long)(rb0 + c_ * 16) * 64;                             \
        gload_lds16(gA_h + rowoff_ + kb_ + g_lane, (Lb) + 0 * 8192 + ldsoff_); \
        gload_lds16(gA_l + rowoff_ + kb_ + g_lane, (Lb) + 1 * 8192 + ldsoff_); \
        gload_lds16(gB_h + rowoff_ + kb_ + g_lane, (Lb) + 2 * 8192 + ldsoff_); \
        gload_lds16(gB_l + rowoff_ + kb_ + g_lane, (Lb) + 3 * 8192 + ldsoff_); \
    } } while (0)

__global__ __launch_bounds__(256) void mfma_gemm_kernel(
    const f16* __restrict__ Ah, const f16* __restrict__ Al, long sA,
    const f16* __restrict__ Bh, const f16* __restrict__ Bl, long sB,
    float* __restrict__ Cp, long sC, int ldC,
    const float* __restrict__ bias, const float* __restrict__ inv_sc,
    float base_sc, int fuseqv)
{
    __shared__ f16 lds[2][4][128 * 32];  // [dbuf][Ah,Al,Bh,Bl]; 64 KB total
    int bz = blockIdx.z;
    int n0 = blockIdx.x * 128, m0 = blockIdx.y * 128;
    int t = threadIdx.x;
    int lane = t & 63, wid = t >> 6;
    int wy = wid >> 1, wx = wid & 1;

    // staging: physical chunk = lane&3, logical chunk = (lane&3)^((row>>1)&3)
    int cl = (lane & 3) ^ ((lane >> 3) & 3);
    long g_lane = (long)(lane >> 2) * 1024 + (long)cl * 16;   // row = 512 f16 = 1024 B

    const char* gA_h = (const char*)(Ah + bz * sA) + (long)m0 * 1024;
    const char* gA_l = (const char*)(Al + bz * sA) + (long)m0 * 1024;
    const char* gB_h = (const char*)(Bh + bz * sB) + (long)n0 * 1024;
    const char* gB_l = (const char*)(Bl + bz * sB) + (long)n0 * 1024;

    char* L0 = (char*)&lds[0][0][0];
    int rb0 = wid * 32;                  // this wave stages rows rb0..rb0+31

    // frag read: want logical chunk (lane>>4); read physical
    int cp = (lane >> 4) ^ (((lane & 15) >> 1) & 3);
    long offA = (long)(wy * 64 + (lane & 15)) * 64 + (long)cp * 16;
    long offB = (long)(wx * 64 + (lane & 15)) * 64 + (long)cp * 16;

    f32x4 acc[4][4];
    #pragma unroll
    for (int i = 0; i < 4; ++i)
        #pragma unroll
        for (int j = 0; j < 4; ++j)
            acc[i][j] = (f32x4){0.f, 0.f, 0.f, 0.f};

    STAGE(L0, 0);
    asm volatile("s_waitcnt vmcnt(0)" ::: "memory");
    __syncthreads();

    for (int s = 0; s < 16; ++s) {
        char* Lc = L0 + ((s & 1) << 15);
        if (s < 15) {
            char* Ln = L0 + (((s + 1) & 1) << 15);
            STAGE(Ln, (s + 1) * 32);
        }

        half8 ah[4], al[4], bh[4], bl[4];
        #pragma unroll
        for (int i = 0; i < 4; ++i) {
            ah[i] = *(const half8*)(Lc + 0 * 8192 + offA + i * 1024);
            al[i] = *(const half8*)(Lc + 1 * 8192 + offA + i * 1024);
            bh[i] = *(const half8*)(Lc + 2 * 8192 + offB + i * 1024);
            bl[i] = *(const half8*)(Lc + 3 * 8192 + offB + i * 1024);
        }
        #pragma unroll
        for (int i = 0; i < 4; ++i)
            #pragma unroll
            for (int j = 0; j < 4; ++j) {
                acc[i][j] = __builtin_amdgcn_mfma_f32_16x16x32_f16(ah[i], bh[j], acc[i][j], 0, 0, 0);
                acc[i][j] = __builtin_amdgcn_mfma_f32_16x16x32_f16(ah[i], bl[j], acc[i][j], 0, 0, 0);
                acc[i][j] = __builtin_amdgcn_mfma_f32_16x16x32_f16(al[i], bh[j], acc[i][j], 0, 0, 0);
            }

        asm volatile("s_waitcnt vmcnt(0)" ::: "memory");
        __syncthreads();
    }

    // C/D layout: col = lane&15, row = (lane>>4)*4 + reg
    int colb = n0 + wx * 64 + (lane & 15);
    int rowb = m0 + wy * 64 + ((lane >> 4) << 2);

    if (fuseqv && m0 < 512) {
        // q third: this wave's 64 rows = head h. Fused softmax over d +
        // split-f16 write (value = p*32 = q_s*256) into q region, [n][512].
        int h = (m0 >> 6) + wy;
        f16* qh_b = (f16*)(Cp + (long)bz * sC);
        f16* ql_b = qh_b + (long)CD * NN;
        // scale logits
        #pragma unroll
        for (int i = 0; i < 4; ++i)
            #pragma unroll
            for (int j = 0; j < 4; ++j)
                #pragma unroll
                for (int r = 0; r < 4; ++r)
                    acc[i][j][r] *= base_sc;
        #pragma unroll
        for (int j = 0; j < 4; ++j) {
            float mx = -INFINITY;
            #pragma unroll
            for (int i = 0; i < 4; ++i)
                #pragma unroll
                for (int r = 0; r < 4; ++r)
                    mx = fmaxf(mx, acc[i][j][r]);
            mx = fmaxf(mx, __shfl_xor(mx, 16));
            mx = fmaxf(mx, __shfl_xor(mx, 32));
            float sum = 0.f;
            #pragma unroll
            for (int i = 0; i < 4; ++i)
                #pragma unroll
                for (int r = 0; r < 4; ++r) {
                    float e = expf(acc[i][j][r] - mx);
                    acc[i][j][r] = e;
                    sum += e;
                }
            sum += __shfl_xor(sum, 16);
            sum += __shfl_xor(sum, 32);
            float rj = 32.f / sum;
            long nj = colb + j * 16;
            long off = nj * CD + h * 64 + ((lane >> 4) << 2);
            #pragma unroll
            for (int i = 0; i < 4; ++i) {
                half4v hh, ll;
                #pragma unroll
                for (int r = 0; r < 4; ++r) {
                    float v = acc[i][j][r] * rj;
                    f16 hv = (f16)v;
                    hh[r] = hv;
                    ll[r] = (f16)(v - (float)hv);
                }
                *(half4v*)(qh_b + off + i * 16) = hh;
                *(half4v*)(ql_b + off + i * 16) = ll;
            }
        }
        return;
    }

    if (fuseqv && m0 >= 1024) {
        // v third: emit split-f16 (value = v_true * 16) into qkv's v region
        f16* vhp = (f16*)(Cp + (long)bz * sC + 2L * CD * NN);
        f16* vlp = vhp + (long)CD * NN;
        float vsc = base_sc * 16.f;
        #pragma unroll
        for (int i = 0; i < 4; ++i)
            #pragma unroll
            for (int j = 0; j < 4; ++j)
                #pragma unroll
                for (int r = 0; r < 4; ++r) {
                    long row = rowb + i * 16 + r - 1024;
                    float val = acc[i][j][r] * vsc;
                    f16 hv = (f16)val;
                    vhp[row * NN + colb + j * 16] = hv;
                    vlp[row * NN + colb + j * 16] = (f16)(val - (float)hv);
                }
        return;
    }

    float* outp = Cp + bz * sC;
    float mult = base_sc * (inv_sc ? inv_sc[bz] : 1.f);
    #pragma unroll
    for (int i = 0; i < 4; ++i)
        #pragma unroll
        for (int j = 0; j < 4; ++j)
            #pragma unroll
            for (int r = 0; r < 4; ++r) {
                int row = rowb + i * 16 + r;
                float bb = bias ? bias[row] : 0.f;
                outp[(long)row * ldC + colb + j * 16] = acc[i][j][r] * mult + bb;
            }
}

// ---------------------------------------------------------------------------
// k softmax over tokens (4096 contiguous); emit split-f16 k_s * 4096 into
// d_out (xth/xtl are dead after the qkv GEMM): per batch kh [512][4096],
// kl [512][4096].
// ---------------------------------------------------------------------------
__global__ __launch_bounds__(256) void softmax_k_kernel(
    const float* __restrict__ qkv, f16* __restrict__ ksp)
{
    int row = blockIdx.x;              // b*512 + hd
    int b = row >> 9;
    int hd = row & (CD - 1);
    const float* base = qkv + ((long)b * OC3 + CD + hd) * NN;
    f16* khb = ksp + (long)b * 2 * CD * NN + (long)hd * NN;
    f16* klb = khb + (long)CD * NN;
    int t = threadIdx.x;

    float v[16];
    #pragma unroll
    for (int i = 0; i < 16; ++i) v[i] = base[t + i * 256];

    __shared__ float red[256];
    float mx = -INFINITY;
    #pragma unroll
    for (int i = 0; i < 16; ++i) mx = fmaxf(mx, v[i]);
    red[t] = mx; __syncthreads();
    for (int off = 128; off > 0; off >>= 1) {
        if (t < off) red[t] = fmaxf(red[t], red[t + off]);
        __syncthreads();
    }
    mx = red[0]; __syncthreads();

    float s = 0.f;
    #pragma unroll
    for (int i = 0; i < 16; ++i) {
        v[i] = expf(v[i] - mx);
        s += v[i];
    }
    red[t] = s; __syncthreads();
    for (int off = 128; off > 0; off >>= 1) {
        if (t < off) red[t] += red[t + off];
        __syncthreads();
    }
    float inv = 4096.f / red[0];       // k_s scaled by 2^12 for f16 split

    #pragma unroll
    for (int i = 0; i < 16; ++i) {
        float val = v[i] * inv;
        f16 hv = (f16)val;
        khb[t + i * 256] = hv;
        klb[t + i * 256] = (f16)(val - (float)hv);
    }
}

// ---------------------------------------------------------------------------
// context partials via split-f16 MFMA: per (bh, sp) block computes
// acc[64 d][64 e] = sum over 256 n of (k_s*2^12)(v*2^4), 3 products.
// k from d_out (ksp), v from qkv's v region.
// ---------------------------------------------------------------------------
__global__ __launch_bounds__(256) void ctx_mfma_kernel(
    const f16* __restrict__ ksp, const float* __restrict__ qkv,
    float* __restrict__ ctxp)
{
    __shared__ f16 lds[4][64 * 32];          // kh,kl,vh,vl tiles; 4 KB each
    int sp = blockIdx.x;                     // K-split 0..15
    int bh = blockIdx.y;                     // 0..63
    int b = bh >> 3, h = bh & 7;
    int t = threadIdx.x, lane = t & 63, w = t >> 6;

    const char* khg = (const char*)(ksp + (long)b * 2 * CD * NN) + (long)h * 64 * (NN * 2);
    const char* klg = khg + (long)CD * NN * 2;
    const char* vhg = (const char*)(qkv + ((long)b * OC3 + 2L * CD) * NN) + (long)h * 64 * (NN * 2);
    const char* vlg = vhg + (long)CD * NN * 2;
    const char* gw = (w == 0) ? khg : (w == 1) ? klg : (w == 2) ? vhg : vlg;

    int cl = (lane & 3) ^ ((lane >> 3) & 3);
    char* larr = (char*)&lds[0][0] + w * 4096;
    char* L = (char*)&lds[0][0];
    int cp16 = ((lane >> 4) ^ (((lane & 15) >> 1) & 3)) * 16;
    int lr = lane & 15;

    f32x4 acc[4];
    #pragma unroll
    for (int i = 0; i < 4; ++i) acc[i] = (f32x4){0.f, 0.f, 0.f, 0.f};

    for (int ks = 0; ks < 8; ++ks) {
        long kbyte = ((long)sp * 256 + ks * 32) * 2;
        #pragma unroll
        for (int c = 0; c < 4; ++c)
            gload_lds16(gw + (long)(c * 16 + (lane >> 2)) * (NN * 2) + kbyte + (long)cl * 16,
                        larr + c * 1024 + lane * 16);
        asm volatile("s_waitcnt vmcnt(0)" ::: "memory");
        __syncthreads();

        half8 ah[4], al[4], bhf, blf;
        #pragma unroll
        for (int i = 0; i < 4; ++i) {
            ah[i] = *(const half8*)(L + 0 * 4096 + (i * 16 + lr) * 64 + cp16);
            al[i] = *(const half8*)(L + 1 * 4096 + (i * 16 + lr) * 64 + cp16);
        }
        bhf = *(const half8*)(L + 2 * 4096 + (w * 16 + lr) * 64 + cp16);
        blf = *(const half8*)(L + 3 * 4096 + (w * 16 + lr) * 64 + cp16);
        #pragma unroll
        for (int i = 0; i < 4; ++i) {
            acc[i] = __builtin_amdgcn_mfma_f32_16x16x32_f16(ah[i], bhf, acc[i], 0, 0, 0);
            acc[i] = __builtin_amdgcn_mfma_f32_16x16x32_f16(ah[i], blf, acc[i], 0, 0, 0);
            acc[i] = __builtin_amdgcn_mfma_f32_16x16x32_f16(al[i], bhf, acc[i], 0, 0, 0);
        }
        __syncthreads();
    }

    float* op = ctxp + ((long)bh * NSPLIT + sp) * 4096;
    #pragma unroll
    for (int i = 0; i < 4; ++i)
        #pragma unroll
        for (int r = 0; r < 4; ++r)
            op[(i * 16 + (lane >> 4) * 4 + r) * 64 + w * 16 + lr] = acc[i][r];
}

// ---------------------------------------------------------------------------
// reduce partials in fp64; undo scales: /(2^12 * 2^4) and /N  => * 2^-28
// ---------------------------------------------------------------------------
__global__ __launch_bounds__(256) void context_reduce_kernel(
    const float* __restrict__ ctxp, float* __restrict__ ctx)
{
    int idx = blockIdx.x * 256 + threadIdx.x;
    int bh = idx >> 12;
    int de = idx & 4095;
    double s = 0.0;
    #pragma unroll
    for (int sp = 0; sp < NSPLIT; ++sp)
        s += (double)ctxp[((long)bh * NSPLIT + sp) * 4096 + de];
    ctx[idx] = (float)(s * (1.0 / 268435456.0));
}

// ---------------------------------------------------------------------------
// fold w_out into per-batch M (row-major [c][hd]) — LDS-tiled:
// block = (c-tile 128, bh); ctx[b,h] (64x64) staged once in LDS (65-pad).
// ---------------------------------------------------------------------------
__global__ __launch_bounds__(256) void fold_wout_kernel(
    const float* __restrict__ w_out, const float* __restrict__ ctx,
    float* __restrict__ Mf)
{
    __shared__ float cl[64][65];
    int ct = blockIdx.x;               // c-tile 0..3
    int bh = blockIdx.y;               // b*8+h
    int b = bh >> 3, h = bh & 7;
    int t = threadIdx.x;
    const float* cp = ctx + (long)bh * 4096;
    #pragma unroll
    for (int i = 0; i < 16; ++i) {
        int o = t + i * 256;
        cl[o >> 6][o & 63] = cp[o];
    }
    __syncthreads();

    int d = t & 63, tc = t >> 6;       // 4 c-subgroups of 32
    #pragma unroll 4
    for (int ci = 0; ci < 32; ++ci) {
        int c = ct * 128 + tc * 32 + ci;
        const float* wr = w_out + (long)c * CD + h * DD;
        float s = 0.f;
        #pragma unroll
        for (int e = 0; e < 64; ++e) s += wr[e] * cl[d][e];
        Mf[((long)b * CD + c) * CD + h * DD + d] = s;
    }
}

// ---------------------------------------------------------------------------
// per-batch max|M| two-stage: 32 partial blocks per batch, then final.
// ---------------------------------------------------------------------------
__global__ __launch_bounds__(256) void max_m_part_kernel(
    const float* __restrict__ Mf, float* __restrict__ part)
{
    int blk = blockIdx.x;              // 256 blocks: b = blk>>5, sub = blk&31
    int b = blk >> 5, sub = blk & 31;
    const float4* p = (const float4*)(Mf + (long)b * CD * CD) + (long)sub * 2048;
    float mx = 0.f;
    for (int i = threadIdx.x; i < 2048; i += 256) {
        float4 v = p[i];
        mx = fmaxf(mx, fmaxf(fmaxf(fabsf(v.x), fabsf(v.y)),
                             fmaxf(fabsf(v.z), fabsf(v.w))));
    }
    __shared__ float red[256];
    red[threadIdx.x] = mx; __syncthreads();
    for (int off = 128; off > 0; off >>= 1) {
        if (threadIdx.x < off) red[threadIdx.x] = fmaxf(red[threadIdx.x], red[threadIdx.x + off]);
        __syncthreads();
    }
    if (threadIdx.x == 0) part[blk] = red[0];
}

__global__ __launch_bounds__(64) void max_m_final_kernel(
    const float* __restrict__ part, float* __restrict__ scl)
{
    int b = threadIdx.x;
    if (b < 8) {
        float m = 0.f;
        #pragma unroll
        for (int i = 0; i < 32; ++i) m = fmaxf(m, part[b * 32 + i]);
        int e = (m > 1e-30f) ? ilogbf(m) : 0;
        scl[b] = ldexpf(1.f, 10 - e);
        scl[8 + b] = ldexpf(1.f, e - 10);
    }
}

// ---------------------------------------------------------------------------
// split M fp32 -> mh/ml f16 with per-batch scale
// ---------------------------------------------------------------------------
__global__ __launch_bounds__(256) void split_m_kernel(
    const float* __restrict__ Mf, const float* __restrict__ scl,
    f16* __restrict__ mh, f16* __restrict__ ml)
{
    int idx = blockIdx.x * 256 + threadIdx.x;   // BB*CD*CD/4 float4s
    float s = scl[idx >> 16];                   // 65536 float4s per batch
    float4 v = ((const float4*)Mf)[idx];
    float a[4] = {v.x, v.y, v.z, v.w};
    half4v h, l;
    #pragma unroll
    for (int i = 0; i < 4; ++i) {
        float tval = a[i] * s;
        f16 hv = (f16)tval;
        h[i] = hv;
        l[i] = (f16)(tval - (float)hv);
    }
    *(half4v*)(&mh[(long)idx * 4]) = h;
    *(half4v*)(&ml[(long)idx * 4]) = l;
}

// ---------------------------------------------------------------------------
// channel LayerNorm over c=512 (stride NN), fp64 stats, values reg-cached.
// ---------------------------------------------------------------------------
__global__ __launch_bounds__(256) void layernorm_kernel(
    const float* __restrict__ qkv, const float* __restrict__ g,
    float* __restrict__ out)
{
    int t = threadIdx.x;
    int tn = t & 31, cy = t >> 5;              // col-in-block, c-group
    long col = (long)blockIdx.x * 32 + tn;     // 0..32767
    int n = (int)(col & (NN - 1));
    int b = (int)(col >> 12);
    const float* base = qkv + (long)b * OC3 * NN + (long)CD * NN + n;

    float v[64];
    double s = 0.0, ss = 0.0;
    #pragma unroll
    for (int i = 0; i < 64; ++i) {
        v[i] = base[(long)(cy * 64 + i) * NN];
        s += (double)v[i];
        ss += (double)v[i] * (double)v[i];
    }

    __shared__ double rs[8][32], rss[8][32];
    rs[cy][tn] = s; rss[cy][tn] = ss;
    __syncthreads();
    __shared__ float mb[32], ib[32];
    if (cy == 0) {
        double S = 0.0, SS = 0.0;
        #pragma unroll
        for (int j = 0; j < 8; ++j) { S += rs[j][tn]; SS += rss[j][tn]; }
        double mean = S * (1.0 / CD);
        double var = SS * (1.0 / CD) - mean * mean;
        mb[tn] = (float)mean;
        ib[tn] = (float)(1.0 / sqrt(var + 1e-5));
    }
    __syncthreads();
    float m = mb[tn], iv = ib[tn];

    float* oc = out + (long)b * CD * NN + n;
    #pragma unroll
    for (int i = 0; i < 64; ++i)
        oc[(long)(cy * 64 + i) * NN] = (v[i] - m) * iv * g[cy * 64 + i];
}

// ---------------------------------------------------------------------------
extern "C" void kernel_launch(void* const* d_in, const int* in_sizes, int n_in,
                              void* d_out, int out_size, void* d_ws, size_t ws_size,
                              hipStream_t stream)
{
    const float* x     = (const float*)d_in[0];
    const float* w_qkv = (const float*)d_in[1];
    const float* w_out = (const float*)d_in[2];
    const float* b_out = (const float*)d_in[3];
    const float* g     = (const float*)d_in[4];
    float* out = (float*)d_out;

    float* ws   = (float*)d_ws;
    float* qkv  = ws;                                      // 50,331,648 f
    float* ctxp = qkv + (long)BB * OC3 * NN;               //  4,194,304 f (reused for Mf)
    float* ctx  = ctxp + (long)BB * HH * NSPLIT * DD * DD; //    262,144 f
    f16*   mh   = (f16*)(ctx + (long)BB * HH * DD * DD);   //  2,097,152 h
    f16*   ml   = mh + (long)BB * CD * CD;                 //  2,097,152 h
    f16*   wh   = (f16*)(ml + (long)BB * CD * CD);         //    786,432 h
    f16*   wl   = wh + (long)OC3 * CD;                     //    786,432 h
    float* scl  = (float*)(wl + (long)OC3 * CD);           //         16 f
    float* part = scl + 16;                                //        256 f
    float* Mf   = ctxp;                                    // ctxp dead by then

    // d_out as scratch: xth/xtl (phase 1), then kh/kl (phase 2); LN
    // overwrites at the end.
    f16* xth = (f16*)d_out;
    f16* xtl = xth + (long)BB * NN * CD;
    f16* ksp = (f16*)d_out;   // kh/kl after xth/xtl are consumed

    // 0) operand splits
    split_w_kernel<<<(OC3 * CD / 4) / 256, 256, 0, stream>>>(w_qkv, wh, wl);
    split_x_kernel<<<dim3(NN / 64, CD / 64, BB), 256, 0, stream>>>(x, xth, xtl);

    // 1) qkv = w_qkv @ x via split-f16 MFMA with fused epilogues:
    //    q -> softmax-over-d + split-f16 into q region; k -> fp32;
    //    v -> split-f16 into v region.
    mfma_gemm_kernel<<<dim3(NN / 128, OC3 / 128, BB), 256, 0, stream>>>(
        wh, wl, 0L, xth, xtl, (long)NN * CD,
        qkv, (long)OC3 * NN, NN, nullptr, nullptr, 1.0f / 1024.0f, 1);

    // 2) k softmax -> split-f16 k_s (x4096) into d_out
    softmax_k_kernel<<<BB * CD, 256, 0, stream>>>(qkv, ksp);

    // 3) context via MFMA partials + fp64 reduce (undoes 2^16 scale and /N)
    ctx_mfma_kernel<<<dim3(NSPLIT, BB * HH), 256, 0, stream>>>(ksp, qkv, ctxp);
    context_reduce_kernel<<<(BB * HH * DD * DD) / 256, 256, 0, stream>>>(ctxp, ctx);

    // 4) M = fold(w_out, ctx) fp32 -> dynamic per-batch pow2 scale -> f16 split
    fold_wout_kernel<<<dim3(4, BB * HH), 256, 0, stream>>>(w_out, ctx, Mf);
    max_m_part_kernel<<<256, 256, 0, stream>>>(Mf, part);
    max_m_final_kernel<<<1, 64, 0, stream>>>(part, scl);
    split_m_kernel<<<(BB * CD * CD / 4) / 256, 256, 0, stream>>>(Mf, scl, mh, ml);

    // 5) y = M_b @ q_s + b_out via split-f16 MFMA -> dead k region of qkv
    //    B operand = qh/ql in the q region of qkv ([n][512] layout)
    mfma_gemm_kernel<<<dim3(NN / 128, CD / 128, BB), 256, 0, stream>>>(
        mh, ml, (long)CD * CD,
        (const f16*)qkv, (const f16*)qkv + (long)CD * NN, (long)OC3 * NN * 2,
        qkv + (long)CD * NN, (long)OC3 * NN, NN, b_out, scl + 8, 1.0f / 256.0f,
        0);

    // 6) channel LayerNorm -> d_out (overwrites k scratch)
    layernorm_kernel<<<(BB * NN) / 32, 256, 0, stream>>>(qkv, g, out);
}